// Round 1
// baseline (400.911 us; speedup 1.0000x reference)
//
#include <hip/hip_runtime.h>
#include <hip/hip_bf16.h>

// PNAConvTower: h' = BN( snorm * ([x, PNA_aggr(x)] @ Wu + bu) )
// msg[e] = A[src[e]] + B[dst[e]] + bm   where A = x@Wm[:64], B = x@Wm[64:]
// aggr: mean/max/min/std over incoming edges, 3 scalers (id, log(D+1)/delta, delta/log(D+1))

#define DELTA_C 2.83f
#define BN_EPS_C 1e-5f
#define MOM_EPS_C 1e-30f

// ---------------- K1: A = x @ Wm_top, B = x @ Wm_bot -----------------------
__global__ __launch_bounds__(256) void proj_ab(
    const float* __restrict__ x, const float* __restrict__ Wm,
    float* __restrict__ A, float* __restrict__ B, int n)
{
    __shared__ float wm[128][68];
    __shared__ float xs[64][68];
    int t = threadIdx.x;
    // stage Wm (128x64) fully
    for (int i = t; i < 2048; i += 256) {
        int k = i >> 4, c4 = (i & 15) << 2;
        *(float4*)&wm[k][c4] = *(const float4*)&Wm[k * 64 + c4];
    }
    int row0 = blockIdx.x * 64;
    for (int i = t; i < 1024; i += 256) {
        int r = i >> 4, k4 = (i & 15) << 2;
        int row = row0 + r;
        float4 v = make_float4(0.f, 0.f, 0.f, 0.f);
        if (row < n) v = *(const float4*)&x[(size_t)row * 64 + k4];
        *(float4*)&xs[r][k4] = v;
    }
    __syncthreads();
    int tr = t >> 4, tc = t & 15, c0 = tc << 2;
    float a[4][4] = {}; float b[4][4] = {};
    #pragma unroll 8
    for (int k = 0; k < 64; ++k) {
        float4 wa = *(float4*)&wm[k][c0];
        float4 wb = *(float4*)&wm[64 + k][c0];
        #pragma unroll
        for (int i = 0; i < 4; ++i) {
            float xv = xs[tr * 4 + i][k];
            a[i][0] += xv * wa.x; a[i][1] += xv * wa.y; a[i][2] += xv * wa.z; a[i][3] += xv * wa.w;
            b[i][0] += xv * wb.x; b[i][1] += xv * wb.y; b[i][2] += xv * wb.z; b[i][3] += xv * wb.w;
        }
    }
    #pragma unroll
    for (int i = 0; i < 4; ++i) {
        int row = row0 + tr * 4 + i;
        if (row < n) {
            float4 va = make_float4(a[i][0], a[i][1], a[i][2], a[i][3]);
            float4 vb = make_float4(b[i][0], b[i][1], b[i][2], b[i][3]);
            *(float4*)&A[(size_t)row * 64 + c0] = va;
            *(float4*)&B[(size_t)row * 64 + c0] = vb;
        }
    }
}

// ---------------- K2: degree count -----------------------------------------
__global__ void count_deg(const int* __restrict__ dst, int* __restrict__ deg, int e)
{
    int i = blockIdx.x * blockDim.x + threadIdx.x;
    if (i < e) atomicAdd(&deg[dst[i]], 1);
}

// ---------------- K3: exclusive prefix sum (single block) -------------------
__global__ __launch_bounds__(1024) void scan_deg(
    const int* __restrict__ deg, int* __restrict__ offs,
    int* __restrict__ cursor, int n)
{
    __shared__ int buf[1024];
    __shared__ int carry_s;
    int t = threadIdx.x;
    if (t == 0) carry_s = 0;
    __syncthreads();
    for (int base = 0; base < n; base += 1024) {
        int i = base + t;
        int v = (i < n) ? deg[i] : 0;
        buf[t] = v;
        __syncthreads();
        #pragma unroll
        for (int s = 1; s < 1024; s <<= 1) {
            int add = (t >= s) ? buf[t - s] : 0;
            __syncthreads();
            buf[t] += add;
            __syncthreads();
        }
        int incl = buf[t];
        int carry = carry_s;
        if (i < n) { int ex = carry + incl - v; offs[i] = ex; cursor[i] = ex; }
        __syncthreads();
        if (t == 1023) carry_s = carry + incl;
        __syncthreads();
    }
    if (t == 0) offs[n] = carry_s;
}

// ---------------- K4: scatter src into CSR ---------------------------------
__global__ void fill_csr(const int* __restrict__ src, const int* __restrict__ dst,
                         int* __restrict__ cursor, int* __restrict__ csr, int e)
{
    int i = blockIdx.x * blockDim.x + threadIdx.x;
    if (i < e) {
        int p = atomicAdd(&cursor[dst[i]], 1);
        csr[p] = src[i];
    }
}

// ---------------- K5: per-node multi-stat reduction (1 wave / node) ---------
__global__ __launch_bounds__(256) void node_reduce(
    const float* __restrict__ A, const float* __restrict__ Bp, const float* __restrict__ bm,
    const int* __restrict__ offs, const int* __restrict__ csr,
    float* __restrict__ h, float* __restrict__ s1, float* __restrict__ s2, int n)
{
    int wid = threadIdx.x >> 6;
    int lane = threadIdx.x & 63;
    int node = blockIdx.x * 4 + wid;
    if (node >= n) return;
    int beg = offs[node], end = offs[node + 1];
    int dg = end - beg;
    float* hrow = &h[(size_t)node * 256];
    if (dg == 0) {
        hrow[lane] = 0.f; hrow[64 + lane] = 0.f; hrow[128 + lane] = 0.f; hrow[192 + lane] = 0.f;
        if (lane == 0) { s1[node] = 0.f; s2[node] = 0.f; }
        return;
    }
    float bn = Bp[(size_t)node * 64 + lane] + bm[lane];
    float s = 0.f, ss = 0.f, mx = -3.402823466e38f, mn = 3.402823466e38f;
    for (int j = beg; j < end; ++j) {
        int si = csr[j];                       // wave-uniform -> scalar load
        float v = A[(size_t)si * 64 + lane] + bn;   // coalesced 256B line
        s += v; ss += v * v;
        mx = fmaxf(mx, v); mn = fminf(mn, v);
    }
    float fd = (float)dg;
    float mean = s / fd;
    float var = ss / fd - mean * mean;
    if (var < 0.f) var = 0.f;
    float sd = sqrtf(var + MOM_EPS_C);
    hrow[lane] = mean; hrow[64 + lane] = mx; hrow[128 + lane] = mn; hrow[192 + lane] = sd;
    if (lane == 0) {
        float logD = logf(fd + 1.0f);
        s1[node] = logD / DELTA_C;
        s2[node] = DELTA_C / logD;
    }
}

// ---------------- K6: z = (x@W0 + h@W1 + s1*(h@W2) + s2*(h@W3) + bu)*snorm --
__global__ __launch_bounds__(256) void gemm_update(
    const float* __restrict__ x, const float* __restrict__ h,
    const float* __restrict__ s1, const float* __restrict__ s2,
    const float* __restrict__ Wu, const float* __restrict__ bu,
    float* __restrict__ z, int n, float snorm)
{
    __shared__ float aS[64][68];
    __shared__ float w0[64][68];
    __shared__ float w1[64][68];
    __shared__ float w2[64][68];
    int t = threadIdx.x;
    int row0 = blockIdx.x * 64;
    int tr = t >> 4, tc = t & 15, c0 = tc << 2;
    float acc0[4][4] = {}, acc1[4][4] = {}, acc2[4][4] = {};

    // ---- chunk 0: x @ Wu[0:64] ----
    for (int i = t; i < 1024; i += 256) {
        int r = i >> 4, k4 = (i & 15) << 2;
        int row = row0 + r;
        float4 v = make_float4(0.f, 0.f, 0.f, 0.f);
        if (row < n) v = *(const float4*)&x[(size_t)row * 64 + k4];
        *(float4*)&aS[r][k4] = v;
    }
    for (int i = t; i < 1024; i += 256) {
        int kk = i >> 4, c4 = (i & 15) << 2;
        *(float4*)&w0[kk][c4] = *(const float4*)&Wu[(size_t)kk * 64 + c4];
    }
    __syncthreads();
    #pragma unroll 8
    for (int kk = 0; kk < 64; ++kk) {
        float4 b0 = *(float4*)&w0[kk][c0];
        #pragma unroll
        for (int i = 0; i < 4; ++i) {
            float av = aS[tr * 4 + i][kk];
            acc0[i][0] += av * b0.x; acc0[i][1] += av * b0.y;
            acc0[i][2] += av * b0.z; acc0[i][3] += av * b0.w;
        }
    }

    // ---- h chunks: each staged once, used against 3 weight tiles ----
    for (int g = 0; g < 4; ++g) {
        __syncthreads();
        for (int i = t; i < 1024; i += 256) {
            int r = i >> 4, k4 = (i & 15) << 2;
            int row = row0 + r;
            float4 v = make_float4(0.f, 0.f, 0.f, 0.f);
            if (row < n) v = *(const float4*)&h[(size_t)row * 256 + g * 64 + k4];
            *(float4*)&aS[r][k4] = v;
        }
        for (int i = t; i < 1024; i += 256) {
            int kk = i >> 4, c4 = (i & 15) << 2;
            *(float4*)&w0[kk][c4] = *(const float4*)&Wu[(size_t)(64  + g * 64 + kk) * 64 + c4];
            *(float4*)&w1[kk][c4] = *(const float4*)&Wu[(size_t)(320 + g * 64 + kk) * 64 + c4];
            *(float4*)&w2[kk][c4] = *(const float4*)&Wu[(size_t)(576 + g * 64 + kk) * 64 + c4];
        }
        __syncthreads();
        #pragma unroll 4
        for (int kk = 0; kk < 64; ++kk) {
            float4 b0 = *(float4*)&w0[kk][c0];
            float4 b1 = *(float4*)&w1[kk][c0];
            float4 b2 = *(float4*)&w2[kk][c0];
            #pragma unroll
            for (int i = 0; i < 4; ++i) {
                float av = aS[tr * 4 + i][kk];
                acc0[i][0] += av * b0.x; acc0[i][1] += av * b0.y;
                acc0[i][2] += av * b0.z; acc0[i][3] += av * b0.w;
                acc1[i][0] += av * b1.x; acc1[i][1] += av * b1.y;
                acc1[i][2] += av * b1.z; acc1[i][3] += av * b1.w;
                acc2[i][0] += av * b2.x; acc2[i][1] += av * b2.y;
                acc2[i][2] += av * b2.z; acc2[i][3] += av * b2.w;
            }
        }
    }

    // ---- epilogue ----
    float4 bv = *(const float4*)&bu[c0];
    #pragma unroll
    for (int i = 0; i < 4; ++i) {
        int row = row0 + tr * 4 + i;
        if (row < n) {
            float v1 = s1[row], v2 = s2[row];
            float4 o;
            o.x = (acc0[i][0] + v1 * acc1[i][0] + v2 * acc2[i][0] + bv.x) * snorm;
            o.y = (acc0[i][1] + v1 * acc1[i][1] + v2 * acc2[i][1] + bv.y) * snorm;
            o.z = (acc0[i][2] + v1 * acc1[i][2] + v2 * acc2[i][2] + bv.z) * snorm;
            o.w = (acc0[i][3] + v1 * acc1[i][3] + v2 * acc2[i][3] + bv.w) * snorm;
            *(float4*)&z[(size_t)row * 64 + c0] = o;
        }
    }
}

// ---------------- K7: BN column stats --------------------------------------
__global__ __launch_bounds__(256) void bn_stats(
    const float* __restrict__ z, float* __restrict__ acc, int n)
{
    int t = threadIdx.x;
    int c = t & 63, rg = t >> 6;
    float s = 0.f, ss = 0.f;
    for (int r = blockIdx.x * 4 + rg; r < n; r += gridDim.x * 4) {
        float v = z[(size_t)r * 64 + c];
        s += v; ss += v * v;
    }
    __shared__ float sb[256], ssb[256];
    sb[t] = s; ssb[t] = ss;
    __syncthreads();
    if (t < 128) { sb[t] += sb[t + 128]; ssb[t] += ssb[t + 128]; }
    __syncthreads();
    if (t < 64) {
        atomicAdd(&acc[c], sb[t] + sb[t + 64]);
        atomicAdd(&acc[64 + c], ssb[t] + ssb[t + 64]);
    }
}

// ---------------- K8: BN normalize (in place on d_out) ----------------------
__global__ __launch_bounds__(256) void bn_apply(
    float* __restrict__ z, const float* __restrict__ acc,
    const float* __restrict__ gamma, const float* __restrict__ beta, int n)
{
    float inv_n = 1.0f / (float)n;
    int total = n * 64;
    for (int i = blockIdx.x * blockDim.x + threadIdx.x; i < total; i += gridDim.x * blockDim.x) {
        int c = i & 63;
        float mu = acc[c] * inv_n;
        float var = acc[64 + c] * inv_n - mu * mu;
        if (var < 0.f) var = 0.f;
        float inv = rsqrtf(var + BN_EPS_C);
        z[i] = (z[i] - mu) * inv * gamma[c] + beta[c];
    }
}

extern "C" void kernel_launch(void* const* d_in, const int* in_sizes, int n_in,
                              void* d_out, int out_size, void* d_ws, size_t ws_size,
                              hipStream_t stream)
{
    const float* x     = (const float*)d_in[0];
    const float* Wm    = (const float*)d_in[1];
    const float* bm    = (const float*)d_in[2];
    const float* Wu    = (const float*)d_in[3];
    const float* bu    = (const float*)d_in[4];
    const float* gamma = (const float*)d_in[5];
    const float* beta  = (const float*)d_in[6];
    const int*   src   = (const int*)d_in[7];
    const int*   dst   = (const int*)d_in[8];

    int n = in_sizes[0] / 64;
    int e = in_sizes[7];
    float* z = (float*)d_out;

    // workspace layout (256B aligned slices)
    char* w = (char*)d_ws;
    size_t off = 0;
    auto take = [&](size_t bytes) -> void* {
        void* p = w + off;
        off = (off + bytes + 255) & ~(size_t)255;
        return p;
    };
    float* A      = (float*)take((size_t)n * 64 * sizeof(float));
    float* B      = (float*)take((size_t)n * 64 * sizeof(float));
    float* h      = (float*)take((size_t)n * 256 * sizeof(float));
    float* s1     = (float*)take((size_t)n * sizeof(float));
    float* s2     = (float*)take((size_t)n * sizeof(float));
    int*   deg    = (int*)take((size_t)n * sizeof(int));
    int*   offs   = (int*)take((size_t)(n + 1) * sizeof(int));
    int*   cursor = (int*)take((size_t)n * sizeof(int));
    int*   csr    = (int*)take((size_t)e * sizeof(int));
    float* bnacc  = (float*)take(128 * sizeof(float));

    (void)n_in; (void)out_size; (void)ws_size;

    hipMemsetAsync(deg, 0, (size_t)n * sizeof(int), stream);
    hipMemsetAsync(bnacc, 0, 128 * sizeof(float), stream);

    int nb_rows = (n + 63) / 64;
    int nb_edge = (e + 255) / 256;

    proj_ab<<<nb_rows, 256, 0, stream>>>(x, Wm, A, B, n);
    count_deg<<<nb_edge, 256, 0, stream>>>(dst, deg, e);
    scan_deg<<<1, 1024, 0, stream>>>(deg, offs, cursor, n);
    fill_csr<<<nb_edge, 256, 0, stream>>>(src, dst, cursor, csr, e);
    node_reduce<<<(n + 3) / 4, 256, 0, stream>>>(A, B, bm, offs, csr, h, s1, s2, n);

    float snorm = (float)(1.0 / sqrt((double)n));
    gemm_update<<<nb_rows, 256, 0, stream>>>(x, h, s1, s2, Wu, bu, z, n, snorm);

    bn_stats<<<512, 256, 0, stream>>>(z, bnacc, n);
    bn_apply<<<1024, 256, 0, stream>>>(z, bnacc, gamma, beta, n);
}

// Round 2
// 261.119 us; speedup vs baseline: 1.5354x; 1.5354x over previous
//
#include <hip/hip_runtime.h>
#include <hip/hip_bf16.h>

// PNAConvTower: h' = BN( snorm * ([x, PNA_aggr(x)] @ Wu + bu) )
// msg[e] = A[src[e]] + B[dst[e]] + bm   where A = x@Wm[:64], B = x@Wm[64:]
// z = x@W0 + h@W1 + s1*(h@W2) + s2*(h@W3) + bu  (scalers folded, bf16 MFMA)

#define DELTA_C 2.83f
#define BN_EPS_C 1e-5f
#define MOM_EPS_C 1e-30f

typedef __attribute__((ext_vector_type(8))) short bf16x8;   // 8 bf16 (4 VGPRs)
typedef __attribute__((ext_vector_type(4))) float f32x4;    // MFMA C/D frag

static __device__ __forceinline__ unsigned short f2bf(float f) {
    unsigned u = __float_as_uint(f);
    unsigned r = (u + 0x7FFFu + ((u >> 16) & 1u)) >> 16;    // RNE
    return (unsigned short)r;
}

// ---------------- K0a: x -> bf16 (with zero tail padding) -------------------
__global__ __launch_bounds__(256) void convert_x(
    const float* __restrict__ x, short* __restrict__ xb, int n64, int npad64)
{
    int i = (blockIdx.x * 256 + threadIdx.x) * 8;
    if (i >= npad64) return;
    unsigned short o[8];
    #pragma unroll
    for (int j = 0; j < 8; ++j)
        o[j] = (i + j < n64) ? f2bf(x[i + j]) : (unsigned short)0;
    uint4 u;
    u.x = o[0] | ((unsigned)o[1] << 16);
    u.y = o[2] | ((unsigned)o[3] << 16);
    u.z = o[4] | ((unsigned)o[5] << 16);
    u.w = o[6] | ((unsigned)o[7] << 16);
    *(uint4*)(xb + i) = u;
}

// ---------------- K0b: repack Wu (832x64 f32) into bf16 fragment order ------
// Wup layout: [chunk(26)][cfrag(4)][lane(64)][i(8)]
//   k_global = chunk*32 + (lane>>4)*8 + i ; col = cfrag*16 + (lane&15)
__global__ __launch_bounds__(256) void repack_wu(
    const float* __restrict__ Wu, short* __restrict__ Wup)
{
    int idx = blockIdx.x * 256 + threadIdx.x;
    if (idx >= 26 * 4 * 64) return;
    int lane = idx & 63, c = (idx >> 6) & 3, kc = idx >> 8;
    int kbase = kc * 32 + (lane >> 4) * 8;
    int col = c * 16 + (lane & 15);
    unsigned short o[8];
    #pragma unroll
    for (int i = 0; i < 8; ++i)
        o[i] = f2bf(Wu[(size_t)(kbase + i) * 64 + col]);
    uint4 u;
    u.x = o[0] | ((unsigned)o[1] << 16);
    u.y = o[2] | ((unsigned)o[3] << 16);
    u.z = o[4] | ((unsigned)o[5] << 16);
    u.w = o[6] | ((unsigned)o[7] << 16);
    *(uint4*)(Wup + (size_t)idx * 8) = u;
}

// ---------------- K1: A = x @ Wm_top, B = x @ Wm_bot -----------------------
__global__ __launch_bounds__(256) void proj_ab(
    const float* __restrict__ x, const float* __restrict__ Wm,
    float* __restrict__ A, float* __restrict__ B, int n)
{
    __shared__ float wm[128][68];
    __shared__ float xs[64][68];
    int t = threadIdx.x;
    for (int i = t; i < 2048; i += 256) {
        int k = i >> 4, c4 = (i & 15) << 2;
        *(float4*)&wm[k][c4] = *(const float4*)&Wm[k * 64 + c4];
    }
    int row0 = blockIdx.x * 64;
    for (int i = t; i < 1024; i += 256) {
        int r = i >> 4, k4 = (i & 15) << 2;
        int row = row0 + r;
        float4 v = make_float4(0.f, 0.f, 0.f, 0.f);
        if (row < n) v = *(const float4*)&x[(size_t)row * 64 + k4];
        *(float4*)&xs[r][k4] = v;
    }
    __syncthreads();
    int tr = t >> 4, tc = t & 15, c0 = tc << 2;
    float a[4][4] = {}; float b[4][4] = {};
    #pragma unroll 8
    for (int k = 0; k < 64; ++k) {
        float4 wa = *(float4*)&wm[k][c0];
        float4 wb = *(float4*)&wm[64 + k][c0];
        #pragma unroll
        for (int i = 0; i < 4; ++i) {
            float xv = xs[tr * 4 + i][k];
            a[i][0] += xv * wa.x; a[i][1] += xv * wa.y; a[i][2] += xv * wa.z; a[i][3] += xv * wa.w;
            b[i][0] += xv * wb.x; b[i][1] += xv * wb.y; b[i][2] += xv * wb.z; b[i][3] += xv * wb.w;
        }
    }
    #pragma unroll
    for (int i = 0; i < 4; ++i) {
        int row = row0 + tr * 4 + i;
        if (row < n) {
            *(float4*)&A[(size_t)row * 64 + c0] = make_float4(a[i][0], a[i][1], a[i][2], a[i][3]);
            *(float4*)&B[(size_t)row * 64 + c0] = make_float4(b[i][0], b[i][1], b[i][2], b[i][3]);
        }
    }
}

// ---------------- K2: degree count -----------------------------------------
__global__ void count_deg(const int* __restrict__ dst, int* __restrict__ deg, int e)
{
    int i = blockIdx.x * blockDim.x + threadIdx.x;
    if (i < e) atomicAdd(&deg[dst[i]], 1);
}

// ---------------- K3a/b/c: multi-block exclusive scan ----------------------
__global__ __launch_bounds__(256) void scan_block(
    const int* __restrict__ deg, int* __restrict__ offs, int* __restrict__ bsum, int n)
{
    __shared__ int lds[256];
    int b = blockIdx.x, t = threadIdx.x;
    int base = b * 1024 + t * 4;
    int v[4];
    #pragma unroll
    for (int j = 0; j < 4; ++j) v[j] = (base + j < n) ? deg[base + j] : 0;
    int s = v[0] + v[1] + v[2] + v[3];
    lds[t] = s;
    __syncthreads();
    for (int off = 1; off < 256; off <<= 1) {
        int add = (t >= off) ? lds[t - off] : 0;
        __syncthreads();
        lds[t] += add;
        __syncthreads();
    }
    int p = lds[t] - s;   // exclusive within block
    #pragma unroll
    for (int j = 0; j < 4; ++j) { if (base + j < n) offs[base + j] = p; p += v[j]; }
    if (t == 255) bsum[b] = lds[255];
}

__global__ void scan_carry(const int* __restrict__ bsum, int* __restrict__ boff,
                           int nb, int* __restrict__ offs, int n)
{
    if (blockIdx.x == 0 && threadIdx.x == 0) {
        int acc = 0;
        for (int b = 0; b < nb; ++b) { boff[b] = acc; acc += bsum[b]; }
        offs[n] = acc;
    }
}

__global__ __launch_bounds__(256) void scan_apply(
    int* __restrict__ offs, int* __restrict__ cursor, const int* __restrict__ boff, int n)
{
    int i = blockIdx.x * 256 + threadIdx.x;
    if (i < n) { int v = offs[i] + boff[i >> 10]; offs[i] = v; cursor[i] = v; }
}

// ---------------- K4: scatter src into CSR ---------------------------------
__global__ void fill_csr(const int* __restrict__ src, const int* __restrict__ dst,
                         int* __restrict__ cursor, int* __restrict__ csr, int e)
{
    int i = blockIdx.x * blockDim.x + threadIdx.x;
    if (i < e) {
        int p = atomicAdd(&cursor[dst[i]], 1);
        csr[p] = src[i];
    }
}

// ---------------- K5: per-node multi-stat reduction (1 wave / node) ---------
// writes h in bf16, covers padded rows [n, npad) with zeros
__global__ __launch_bounds__(256) void node_reduce(
    const float* __restrict__ A, const float* __restrict__ Bp, const float* __restrict__ bm,
    const int* __restrict__ offs, const int* __restrict__ csr,
    short* __restrict__ hb, float* __restrict__ s1, float* __restrict__ s2, int n, int npad)
{
    int wid = threadIdx.x >> 6;
    int lane = threadIdx.x & 63;
    int node = blockIdx.x * 4 + wid;
    if (node >= npad) return;
    short* hrow = hb + (size_t)node * 256;
    int beg = 0, dg = 0;
    if (node < n) { beg = offs[node]; dg = offs[node + 1] - beg; }
    if (dg == 0) {
        hrow[lane] = 0; hrow[64 + lane] = 0; hrow[128 + lane] = 0; hrow[192 + lane] = 0;
        if (lane == 0) { s1[node] = 0.f; s2[node] = 0.f; }
        return;
    }
    float bn = Bp[(size_t)node * 64 + lane] + bm[lane];
    float s = 0.f, ss = 0.f, mx = -3.402823466e38f, mn = 3.402823466e38f;
    int end = beg + dg;
    for (int j = beg; j < end; ++j) {
        int si = csr[j];                          // wave-uniform -> scalar load
        float v = A[(size_t)si * 64 + lane] + bn; // coalesced 256B line
        s += v; ss += v * v;
        mx = fmaxf(mx, v); mn = fminf(mn, v);
    }
    float fd = (float)dg;
    float mean = s / fd;
    float var = ss / fd - mean * mean;
    if (var < 0.f) var = 0.f;
    float sd = sqrtf(var + MOM_EPS_C);
    hrow[lane]       = (short)f2bf(mean);
    hrow[64 + lane]  = (short)f2bf(mx);
    hrow[128 + lane] = (short)f2bf(mn);
    hrow[192 + lane] = (short)f2bf(sd);
    if (lane == 0) {
        float logD = logf(fd + 1.0f);
        s1[node] = logD / DELTA_C;
        s2[node] = DELTA_C / logD;
    }
}

// ---------------- K6: MFMA update GEMM -------------------------------------
// block = 256 thr (4 waves), 128 rows; wave = 32 rows (2 strips of 16) x 64 cols
__global__ __launch_bounds__(256) void gemm_mfma(
    const short* __restrict__ xb, const short* __restrict__ hb,
    const float* __restrict__ s1p, const float* __restrict__ s2p,
    const short* __restrict__ Wup, const float* __restrict__ bu,
    float* __restrict__ z, int n, float snorm)
{
    int t = threadIdx.x;
    int lane = t & 63, w = t >> 6;
    int rb = blockIdx.x * 128 + w * 32;
    int r16 = lane & 15, kg = lane >> 4;

    f32x4 accx[2][4] = {};
    f32x4 acc1[2][4] = {};
    f32x4 acc2[2][4] = {};
    f32x4 acc3[2][4] = {};

    const short* xr0 = xb + (size_t)(rb + r16) * 64 + kg * 8;
    const short* xr1 = xr0 + 16 * 64;

    // x @ W0 : global chunks 0..1
    #pragma unroll
    for (int kc = 0; kc < 2; ++kc) {
        bf16x8 a0 = *(const bf16x8*)(xr0 + kc * 32);
        bf16x8 a1 = *(const bf16x8*)(xr1 + kc * 32);
        #pragma unroll
        for (int c = 0; c < 4; ++c) {
            bf16x8 b = *(const bf16x8*)(Wup + (size_t)((kc * 4 + c) * 64 + lane) * 8);
            accx[0][c] = __builtin_amdgcn_mfma_f32_16x16x32_bf16(a0, b, accx[0][c], 0, 0, 0);
            accx[1][c] = __builtin_amdgcn_mfma_f32_16x16x32_bf16(a1, b, accx[1][c], 0, 0, 0);
        }
    }

    const short* hr0 = hb + (size_t)(rb + r16) * 256 + kg * 8;
    const short* hr1 = hr0 + 16 * 256;

    // h @ {W1,W2,W3} : chunks 2+kh / 10+kh / 18+kh
    #pragma unroll 1
    for (int kh = 0; kh < 8; ++kh) {
        bf16x8 a0 = *(const bf16x8*)(hr0 + kh * 32);
        bf16x8 a1 = *(const bf16x8*)(hr1 + kh * 32);
        #pragma unroll
        for (int c = 0; c < 4; ++c) {
            bf16x8 b1 = *(const bf16x8*)(Wup + (size_t)(((2  + kh) * 4 + c) * 64 + lane) * 8);
            bf16x8 b2 = *(const bf16x8*)(Wup + (size_t)(((10 + kh) * 4 + c) * 64 + lane) * 8);
            bf16x8 b3 = *(const bf16x8*)(Wup + (size_t)(((18 + kh) * 4 + c) * 64 + lane) * 8);
            acc1[0][c] = __builtin_amdgcn_mfma_f32_16x16x32_bf16(a0, b1, acc1[0][c], 0, 0, 0);
            acc1[1][c] = __builtin_amdgcn_mfma_f32_16x16x32_bf16(a1, b1, acc1[1][c], 0, 0, 0);
            acc2[0][c] = __builtin_amdgcn_mfma_f32_16x16x32_bf16(a0, b2, acc2[0][c], 0, 0, 0);
            acc2[1][c] = __builtin_amdgcn_mfma_f32_16x16x32_bf16(a1, b2, acc2[1][c], 0, 0, 0);
            acc3[0][c] = __builtin_amdgcn_mfma_f32_16x16x32_bf16(a0, b3, acc3[0][c], 0, 0, 0);
            acc3[1][c] = __builtin_amdgcn_mfma_f32_16x16x32_bf16(a1, b3, acc3[1][c], 0, 0, 0);
        }
    }

    // epilogue: C/D frag layout col=lane&15, row=(lane>>4)*4+reg  [verified]
    #pragma unroll
    for (int s = 0; s < 2; ++s) {
        int r0 = rb + s * 16 + kg * 4;
        float s1v[4], s2v[4];
        #pragma unroll
        for (int r = 0; r < 4; ++r) { s1v[r] = s1p[r0 + r]; s2v[r] = s2p[r0 + r]; }
        #pragma unroll
        for (int c = 0; c < 4; ++c) {
            int col = c * 16 + r16;
            float bval = bu[col];
            #pragma unroll
            for (int r = 0; r < 4; ++r) {
                int row = r0 + r;
                if (row < n) {
                    float v = accx[s][c][r] + acc1[s][c][r]
                            + s1v[r] * acc2[s][c][r] + s2v[r] * acc3[s][c][r] + bval;
                    z[(size_t)row * 64 + col] = v * snorm;
                }
            }
        }
    }
}

// ---------------- K7: BN column stats --------------------------------------
__global__ __launch_bounds__(256) void bn_stats(
    const float* __restrict__ z, float* __restrict__ acc, int n)
{
    int t = threadIdx.x;
    int c = t & 63, rg = t >> 6;
    float s = 0.f, ss = 0.f;
    for (int r = blockIdx.x * 4 + rg; r < n; r += gridDim.x * 4) {
        float v = z[(size_t)r * 64 + c];
        s += v; ss += v * v;
    }
    __shared__ float sb[256], ssb[256];
    sb[t] = s; ssb[t] = ss;
    __syncthreads();
    if (t < 128) { sb[t] += sb[t + 128]; ssb[t] += ssb[t + 128]; }
    __syncthreads();
    if (t < 64) {
        atomicAdd(&acc[c], sb[t] + sb[t + 64]);
        atomicAdd(&acc[64 + c], ssb[t] + ssb[t + 64]);
    }
}

// ---------------- K8: BN normalize (in place on d_out) ----------------------
__global__ __launch_bounds__(256) void bn_apply(
    float* __restrict__ z, const float* __restrict__ acc,
    const float* __restrict__ gamma, const float* __restrict__ beta, int n)
{
    float inv_n = 1.0f / (float)n;
    int total = n * 64;
    for (int i = blockIdx.x * blockDim.x + threadIdx.x; i < total; i += gridDim.x * blockDim.x) {
        int c = i & 63;
        float mu = acc[c] * inv_n;
        float var = acc[64 + c] * inv_n - mu * mu;
        if (var < 0.f) var = 0.f;
        float inv = rsqrtf(var + BN_EPS_C);
        z[i] = (z[i] - mu) * inv * gamma[c] + beta[c];
    }
}

extern "C" void kernel_launch(void* const* d_in, const int* in_sizes, int n_in,
                              void* d_out, int out_size, void* d_ws, size_t ws_size,
                              hipStream_t stream)
{
    const float* x     = (const float*)d_in[0];
    const float* Wm    = (const float*)d_in[1];
    const float* bm    = (const float*)d_in[2];
    const float* Wu    = (const float*)d_in[3];
    const float* bu    = (const float*)d_in[4];
    const float* gamma = (const float*)d_in[5];
    const float* beta  = (const float*)d_in[6];
    const int*   src   = (const int*)d_in[7];
    const int*   dst   = (const int*)d_in[8];

    int n = in_sizes[0] / 64;
    int e = in_sizes[7];
    int npad = ((n + 127) / 128) * 128;
    float* z = (float*)d_out;

    char* w = (char*)d_ws;
    size_t off = 0;
    auto take = [&](size_t bytes) -> void* {
        void* p = w + off;
        off = (off + bytes + 255) & ~(size_t)255;
        return p;
    };
    float* A      = (float*)take((size_t)n * 64 * sizeof(float));
    float* B      = (float*)take((size_t)n * 64 * sizeof(float));
    short* xb     = (short*)take((size_t)npad * 64 * sizeof(short));
    short* hb     = (short*)take((size_t)npad * 256 * sizeof(short));
    float* s1     = (float*)take((size_t)npad * sizeof(float));
    float* s2     = (float*)take((size_t)npad * sizeof(float));
    short* Wup    = (short*)take((size_t)26 * 4 * 64 * 8 * sizeof(short));
    int*   deg    = (int*)take((size_t)n * sizeof(int));
    int*   offs   = (int*)take((size_t)(n + 1) * sizeof(int));
    int*   cursor = (int*)take((size_t)n * sizeof(int));
    int*   csr    = (int*)take((size_t)e * sizeof(int));
    float* bnacc  = (float*)take(128 * sizeof(float));
    int*   bsum   = (int*)take(64 * sizeof(int));
    int*   boff   = (int*)take(64 * sizeof(int));

    (void)n_in; (void)out_size; (void)ws_size;

    hipMemsetAsync(deg, 0, (size_t)n * sizeof(int), stream);
    hipMemsetAsync(bnacc, 0, 128 * sizeof(float), stream);

    int nb_rows64 = (n + 63) / 64;
    int nb_edge = (e + 255) / 256;
    int nb_scan = (n + 1023) / 1024;

    convert_x<<<(npad * 64 / 8 + 255) / 256, 256, 0, stream>>>(x, xb, n * 64, npad * 64);
    repack_wu<<<26, 256, 0, stream>>>(Wu, Wup);
    proj_ab<<<nb_rows64, 256, 0, stream>>>(x, Wm, A, B, n);
    count_deg<<<nb_edge, 256, 0, stream>>>(dst, deg, e);
    scan_block<<<nb_scan, 256, 0, stream>>>(deg, offs, bsum, n);
    scan_carry<<<1, 64, 0, stream>>>(bsum, boff, nb_scan, offs, n);
    scan_apply<<<(n + 255) / 256, 256, 0, stream>>>(offs, cursor, boff, n);
    fill_csr<<<nb_edge, 256, 0, stream>>>(src, dst, cursor, csr, e);
    node_reduce<<<(npad + 3) / 4, 256, 0, stream>>>(A, B, bm, offs, csr, hb, s1, s2, n, npad);

    float snorm = (float)(1.0 / sqrt((double)n));
    gemm_mfma<<<npad / 128, 256, 0, stream>>>(xb, hb, s1, s2, Wup, bu, z, n, snorm);

    bn_stats<<<512, 256, 0, stream>>>(z, bnacc, n);
    bn_apply<<<1024, 256, 0, stream>>>(z, bnacc, gamma, beta, n);
}

// Round 3
// 205.240 us; speedup vs baseline: 1.9534x; 1.2723x over previous
//
#include <hip/hip_runtime.h>
#include <hip/hip_bf16.h>

// PNAConvTower: h' = BN( snorm * ([x, PNA_aggr(x)] @ Wu + bu) )
// msg[e] = A[src[e]] + B[dst[e]] + bm   where A = x@Wm[:64], B = x@Wm[64:]
// Stats are shift-invariant: reduce over A[src] only, add (B[dst]+bm) at the end.
// z = x@W0 + h@W1 + s1*(h@W2) + s2*(h@W3) + bu  (scalers folded, bf16 MFMA)

#define DELTA_C 2.83f
#define BN_EPS_C 1e-5f
#define MOM_EPS_C 1e-30f
#define FLT_BIG 3.402823466e38f

typedef __attribute__((ext_vector_type(8))) short bf16x8;   // 8 bf16 (4 VGPRs)
typedef __attribute__((ext_vector_type(4))) float f32x4;    // MFMA C/D frag

static __device__ __forceinline__ unsigned short f2bf(float f) {
    unsigned u = __float_as_uint(f);
    unsigned r = (u + 0x7FFFu + ((u >> 16) & 1u)) >> 16;    // RNE
    return (unsigned short)r;
}
static __device__ __forceinline__ unsigned pack2(float a, float b) {
    return (unsigned)f2bf(a) | ((unsigned)f2bf(b) << 16);
}
static __device__ __forceinline__ float bflo(unsigned u) { return __uint_as_float(u << 16); }
static __device__ __forceinline__ float bfhi(unsigned u) { return __uint_as_float(u & 0xFFFF0000u); }

// ---------------- K0: repack Wu (832x64 f32) into bf16 fragment order -------
// Wup layout: [chunk(26)][cfrag(4)][lane(64)][i(8)]
//   k_global = chunk*32 + (lane>>4)*8 + i ; col = cfrag*16 + (lane&15)
__global__ __launch_bounds__(256) void repack_wu(
    const float* __restrict__ Wu, short* __restrict__ Wup)
{
    int idx = blockIdx.x * 256 + threadIdx.x;
    if (idx >= 26 * 4 * 64) return;
    int lane = idx & 63, c = (idx >> 6) & 3, kc = idx >> 8;
    int kbase = kc * 32 + (lane >> 4) * 8;
    int col = c * 16 + (lane & 15);
    unsigned short o[8];
    #pragma unroll
    for (int i = 0; i < 8; ++i)
        o[i] = f2bf(Wu[(size_t)(kbase + i) * 64 + col]);
    uint4 u;
    u.x = o[0] | ((unsigned)o[1] << 16);
    u.y = o[2] | ((unsigned)o[3] << 16);
    u.z = o[4] | ((unsigned)o[5] << 16);
    u.w = o[6] | ((unsigned)o[7] << 16);
    *(uint4*)(Wup + (size_t)idx * 8) = u;
}

// ---------------- K1: A(bf16) = x@Wm_top, B(f32) = x@Wm_bot, xb = bf16(x) ---
__global__ __launch_bounds__(256) void proj_ab(
    const float* __restrict__ x, const float* __restrict__ Wm,
    unsigned* __restrict__ Ab, float* __restrict__ B,
    unsigned* __restrict__ xbu, int n)
{
    __shared__ float wm[128][68];
    __shared__ float xs[64][68];
    int t = threadIdx.x;
    for (int i = t; i < 2048; i += 256) {
        int k = i >> 4, c4 = (i & 15) << 2;
        *(float4*)&wm[k][c4] = *(const float4*)&Wm[k * 64 + c4];
    }
    int row0 = blockIdx.x * 64;
    for (int i = t; i < 1024; i += 256) {
        int r = i >> 4, k4 = (i & 15) << 2;
        int row = row0 + r;
        float4 v = make_float4(0.f, 0.f, 0.f, 0.f);
        if (row < n) v = *(const float4*)&x[(size_t)row * 64 + k4];
        *(float4*)&xs[r][k4] = v;
    }
    __syncthreads();
    int tr = t >> 4, tc = t & 15, c0 = tc << 2;
    float a[4][4] = {}; float b[4][4] = {};
    #pragma unroll 8
    for (int k = 0; k < 64; ++k) {
        float4 wa = *(float4*)&wm[k][c0];
        float4 wb = *(float4*)&wm[64 + k][c0];
        #pragma unroll
        for (int i = 0; i < 4; ++i) {
            float xv = xs[tr * 4 + i][k];
            a[i][0] += xv * wa.x; a[i][1] += xv * wa.y; a[i][2] += xv * wa.z; a[i][3] += xv * wa.w;
            b[i][0] += xv * wb.x; b[i][1] += xv * wb.y; b[i][2] += xv * wb.z; b[i][3] += xv * wb.w;
        }
    }
    #pragma unroll
    for (int i = 0; i < 4; ++i) {
        int r = tr * 4 + i;
        int row = row0 + r;
        // xb always (zero-padded rows come from zero-filled xs)
        uint2 xp;
        xp.x = pack2(xs[r][c0], xs[r][c0 + 1]);
        xp.y = pack2(xs[r][c0 + 2], xs[r][c0 + 3]);
        *(uint2*)&xbu[(size_t)row * 32 + (c0 >> 1)] = xp;
        if (row < n) {
            uint2 ap;
            ap.x = pack2(a[i][0], a[i][1]);
            ap.y = pack2(a[i][2], a[i][3]);
            *(uint2*)&Ab[(size_t)row * 32 + (c0 >> 1)] = ap;
            *(float4*)&B[(size_t)row * 64 + c0] = make_float4(b[i][0], b[i][1], b[i][2], b[i][3]);
        }
    }
}

// ---------------- K2: degree count (4 edges/thread) -------------------------
__global__ void count_deg(const int* __restrict__ dst, int* __restrict__ deg, int e)
{
    int i = (blockIdx.x * blockDim.x + threadIdx.x) * 4;
    if (i + 3 < e) {
        int4 d = *(const int4*)(dst + i);
        atomicAdd(&deg[d.x], 1); atomicAdd(&deg[d.y], 1);
        atomicAdd(&deg[d.z], 1); atomicAdd(&deg[d.w], 1);
    } else {
        for (; i < e; ++i) atomicAdd(&deg[dst[i]], 1);
    }
}

// ---------------- K3a/b/c: multi-block exclusive scan ----------------------
__global__ __launch_bounds__(256) void scan_block(
    const int* __restrict__ deg, int* __restrict__ offs, int* __restrict__ bsum, int n)
{
    __shared__ int lds[256];
    int b = blockIdx.x, t = threadIdx.x;
    int base = b * 1024 + t * 4;
    int v[4];
    #pragma unroll
    for (int j = 0; j < 4; ++j) v[j] = (base + j < n) ? deg[base + j] : 0;
    int s = v[0] + v[1] + v[2] + v[3];
    lds[t] = s;
    __syncthreads();
    for (int off = 1; off < 256; off <<= 1) {
        int add = (t >= off) ? lds[t - off] : 0;
        __syncthreads();
        lds[t] += add;
        __syncthreads();
    }
    int p = lds[t] - s;   // exclusive within block
    #pragma unroll
    for (int j = 0; j < 4; ++j) { if (base + j < n) offs[base + j] = p; p += v[j]; }
    if (t == 255) bsum[b] = lds[255];
}

__global__ void scan_carry(const int* __restrict__ bsum, int* __restrict__ boff,
                           int nb, int* __restrict__ offs, int n)
{
    int lane = threadIdx.x;   // 64 threads, nb <= 64 (n <= 65536)
    int v = (lane < nb) ? bsum[lane] : 0;
    int sum = v;
    #pragma unroll
    for (int s = 1; s < 64; s <<= 1) {
        int t = __shfl_up(sum, s);
        if (lane >= s) sum += t;
    }
    if (lane < nb) boff[lane] = sum - v;
    if (lane == 63) offs[n] = sum;
}

__global__ __launch_bounds__(256) void scan_apply(
    int* __restrict__ offs, int* __restrict__ cursor, const int* __restrict__ boff, int n)
{
    int i = blockIdx.x * 256 + threadIdx.x;
    if (i < n) { int v = offs[i] + boff[i >> 10]; offs[i] = v; cursor[i] = v; }
}

// ---------------- K4: scatter src into CSR ---------------------------------
__global__ void fill_csr(const int* __restrict__ src, const int* __restrict__ dst,
                         int* __restrict__ cursor, int* __restrict__ csr, int e)
{
    int i = blockIdx.x * blockDim.x + threadIdx.x;
    if (i < e) {
        int p = atomicAdd(&cursor[dst[i]], 1);
        csr[p] = src[i];
    }
}

// ---------------- K5: per-node multi-stat reduction (1 wave / node) ---------
// bf16 A rows (128B): half-wave per edge -> 2 edges per load instruction.
// Each lane owns 2 columns {2*l32, 2*l32+1}; halves merged via shfl_xor(32).
__global__ __launch_bounds__(256) void node_reduce(
    const unsigned* __restrict__ Ab, const float* __restrict__ Bp,
    const float* __restrict__ bm,
    const int* __restrict__ offs, const int* __restrict__ csr,
    unsigned* __restrict__ hbu, float* __restrict__ s1, float* __restrict__ s2,
    int n, int npad)
{
    int wid = threadIdx.x >> 6;
    int lane = threadIdx.x & 63;
    int node = blockIdx.x * 4 + wid;
    if (node >= npad) return;
    unsigned* hrow = hbu + (size_t)node * 128;   // 256 bf16 = 128 uints
    int l32 = lane & 31;
    int half = lane >> 5;
    int beg = 0, dg = 0;
    if (node < n) { beg = offs[node]; dg = offs[node + 1] - beg; }
    if (dg == 0) {
        if (half == 0) {
            hrow[l32] = 0u; hrow[32 + l32] = 0u; hrow[64 + l32] = 0u; hrow[96 + l32] = 0u;
        }
        if (lane == 0) { s1[node] = 0.f; s2[node] = 0.f; }
        return;
    }

    float s0 = 0.f, s1a = 0.f, ss0 = 0.f, ss1 = 0.f;
    float mx0 = -FLT_BIG, mx1 = -FLT_BIG, mn0 = FLT_BIG, mn1 = FLT_BIG;

#define ACC(u) { float v0 = bflo(u), v1 = bfhi(u);                          \
    s0 += v0; s1a += v1;                                                    \
    ss0 = fmaf(v0, v0, ss0); ss1 = fmaf(v1, v1, ss1);                       \
    mx0 = fmaxf(mx0, v0); mx1 = fmaxf(mx1, v1);                             \
    mn0 = fminf(mn0, v0); mn1 = fminf(mn1, v1); }

    int j = beg, end = beg + dg;
    for (; j + 3 < end; j += 4) {           // 4 edges, 2 independent gathers
        int i0 = csr[j], i1 = csr[j + 1], i2 = csr[j + 2], i3 = csr[j + 3];
        int sa = half ? i1 : i0;
        int sb = half ? i3 : i2;
        unsigned ua = Ab[(size_t)sa * 32 + l32];
        unsigned ub = Ab[(size_t)sb * 32 + l32];
        ACC(ua); ACC(ub);
    }
    for (; j + 1 < end; j += 2) {
        int i0 = csr[j], i1 = csr[j + 1];
        int sa = half ? i1 : i0;
        unsigned ua = Ab[(size_t)sa * 32 + l32];
        ACC(ua);
    }
    if (j < end) {                          // odd tail: half 0 only
        int sa = csr[j];
        unsigned ua = Ab[(size_t)sa * 32 + l32];
        if (half == 0) ACC(ua);
    }
#undef ACC

    // merge the two half-wave edge sets
    s0 += __shfl_xor(s0, 32);  s1a += __shfl_xor(s1a, 32);
    ss0 += __shfl_xor(ss0, 32); ss1 += __shfl_xor(ss1, 32);
    mx0 = fmaxf(mx0, __shfl_xor(mx0, 32)); mx1 = fmaxf(mx1, __shfl_xor(mx1, 32));
    mn0 = fminf(mn0, __shfl_xor(mn0, 32)); mn1 = fminf(mn1, __shfl_xor(mn1, 32));

    float fd = (float)dg, inv = 1.0f / fd;
    float2 bv = *(const float2*)(Bp + (size_t)node * 64 + 2 * l32);
    float2 bmv = *(const float2*)(bm + 2 * l32);
    float bn0 = bv.x + bmv.x, bn1 = bv.y + bmv.y;
    float ma0 = s0 * inv, ma1 = s1a * inv;
    float var0 = ss0 * inv - ma0 * ma0; if (var0 < 0.f) var0 = 0.f;
    float var1 = ss1 * inv - ma1 * ma1; if (var1 < 0.f) var1 = 0.f;
    float sd0 = sqrtf(var0 + MOM_EPS_C), sd1 = sqrtf(var1 + MOM_EPS_C);

    if (half == 0) {
        hrow[l32]      = pack2(ma0 + bn0, ma1 + bn1);
        hrow[32 + l32] = pack2(mx0 + bn0, mx1 + bn1);
        hrow[64 + l32] = pack2(mn0 + bn0, mn1 + bn1);
        hrow[96 + l32] = pack2(sd0, sd1);
    }
    if (lane == 0) {
        float logD = logf(fd + 1.0f);
        s1[node] = logD / DELTA_C;
        s2[node] = DELTA_C / logD;
    }
}

// ---------------- K6: MFMA update GEMM -------------------------------------
// block = 256 thr (4 waves), 128 rows; wave = 32 rows (2 strips of 16) x 64 cols
__global__ __launch_bounds__(256) void gemm_mfma(
    const short* __restrict__ xb, const short* __restrict__ hb,
    const float* __restrict__ s1p, const float* __restrict__ s2p,
    const short* __restrict__ Wup, const float* __restrict__ bu,
    float* __restrict__ z, int n, float snorm)
{
    int t = threadIdx.x;
    int lane = t & 63, w = t >> 6;
    int rb = blockIdx.x * 128 + w * 32;
    int r16 = lane & 15, kg = lane >> 4;

    f32x4 accx[2][4] = {};
    f32x4 acc1[2][4] = {};
    f32x4 acc2[2][4] = {};
    f32x4 acc3[2][4] = {};

    const short* xr0 = xb + (size_t)(rb + r16) * 64 + kg * 8;
    const short* xr1 = xr0 + 16 * 64;

    #pragma unroll
    for (int kc = 0; kc < 2; ++kc) {
        bf16x8 a0 = *(const bf16x8*)(xr0 + kc * 32);
        bf16x8 a1 = *(const bf16x8*)(xr1 + kc * 32);
        #pragma unroll
        for (int c = 0; c < 4; ++c) {
            bf16x8 b = *(const bf16x8*)(Wup + (size_t)((kc * 4 + c) * 64 + lane) * 8);
            accx[0][c] = __builtin_amdgcn_mfma_f32_16x16x32_bf16(a0, b, accx[0][c], 0, 0, 0);
            accx[1][c] = __builtin_amdgcn_mfma_f32_16x16x32_bf16(a1, b, accx[1][c], 0, 0, 0);
        }
    }

    const short* hr0 = hb + (size_t)(rb + r16) * 256 + kg * 8;
    const short* hr1 = hr0 + 16 * 256;

    #pragma unroll 1
    for (int kh = 0; kh < 8; ++kh) {
        bf16x8 a0 = *(const bf16x8*)(hr0 + kh * 32);
        bf16x8 a1 = *(const bf16x8*)(hr1 + kh * 32);
        #pragma unroll
        for (int c = 0; c < 4; ++c) {
            bf16x8 b1 = *(const bf16x8*)(Wup + (size_t)(((2  + kh) * 4 + c) * 64 + lane) * 8);
            bf16x8 b2 = *(const bf16x8*)(Wup + (size_t)(((10 + kh) * 4 + c) * 64 + lane) * 8);
            bf16x8 b3 = *(const bf16x8*)(Wup + (size_t)(((18 + kh) * 4 + c) * 64 + lane) * 8);
            acc1[0][c] = __builtin_amdgcn_mfma_f32_16x16x32_bf16(a0, b1, acc1[0][c], 0, 0, 0);
            acc1[1][c] = __builtin_amdgcn_mfma_f32_16x16x32_bf16(a1, b1, acc1[1][c], 0, 0, 0);
            acc2[0][c] = __builtin_amdgcn_mfma_f32_16x16x32_bf16(a0, b2, acc2[0][c], 0, 0, 0);
            acc2[1][c] = __builtin_amdgcn_mfma_f32_16x16x32_bf16(a1, b2, acc2[1][c], 0, 0, 0);
            acc3[0][c] = __builtin_amdgcn_mfma_f32_16x16x32_bf16(a0, b3, acc3[0][c], 0, 0, 0);
            acc3[1][c] = __builtin_amdgcn_mfma_f32_16x16x32_bf16(a1, b3, acc3[1][c], 0, 0, 0);
        }
    }

    // epilogue: C/D frag layout col=lane&15, row=(lane>>4)*4+reg  [verified]
    #pragma unroll
    for (int s = 0; s < 2; ++s) {
        int r0 = rb + s * 16 + kg * 4;
        float s1v[4], s2v[4];
        #pragma unroll
        for (int r = 0; r < 4; ++r) { s1v[r] = s1p[r0 + r]; s2v[r] = s2p[r0 + r]; }
        #pragma unroll
        for (int c = 0; c < 4; ++c) {
            int col = c * 16 + r16;
            float bval = bu[col];
            #pragma unroll
            for (int r = 0; r < 4; ++r) {
                int row = r0 + r;
                if (row < n) {
                    float v = accx[s][c][r] + acc1[s][c][r]
                            + s1v[r] * acc2[s][c][r] + s2v[r] * acc3[s][c][r] + bval;
                    z[(size_t)row * 64 + col] = v * snorm;
                }
            }
        }
    }
}

// ---------------- K7: BN column stats --------------------------------------
__global__ __launch_bounds__(256) void bn_stats(
    const float* __restrict__ z, float* __restrict__ acc, int n)
{
    int t = threadIdx.x;
    int c = t & 63, rg = t >> 6;
    float s = 0.f, ss = 0.f;
    for (int r = blockIdx.x * 4 + rg; r < n; r += gridDim.x * 4) {
        float v = z[(size_t)r * 64 + c];
        s += v; ss += v * v;
    }
    __shared__ float sb[256], ssb[256];
    sb[t] = s; ssb[t] = ss;
    __syncthreads();
    if (t < 128) { sb[t] += sb[t + 128]; ssb[t] += ssb[t + 128]; }
    __syncthreads();
    if (t < 64) {
        atomicAdd(&acc[c], sb[t] + sb[t + 64]);
        atomicAdd(&acc[64 + c], ssb[t] + ssb[t + 64]);
    }
}

// ---------------- K8: BN normalize (in place on d_out) ----------------------
__global__ __launch_bounds__(256) void bn_apply(
    float* __restrict__ z, const float* __restrict__ acc,
    const float* __restrict__ gamma, const float* __restrict__ beta, int n)
{
    float inv_n = 1.0f / (float)n;
    int total = n * 64;
    for (int i = blockIdx.x * blockDim.x + threadIdx.x; i < total; i += gridDim.x * blockDim.x) {
        int c = i & 63;
        float mu = acc[c] * inv_n;
        float var = acc[64 + c] * inv_n - mu * mu;
        if (var < 0.f) var = 0.f;
        float inv = rsqrtf(var + BN_EPS_C);
        z[i] = (z[i] - mu) * inv * gamma[c] + beta[c];
    }
}

extern "C" void kernel_launch(void* const* d_in, const int* in_sizes, int n_in,
                              void* d_out, int out_size, void* d_ws, size_t ws_size,
                              hipStream_t stream)
{
    const float* x     = (const float*)d_in[0];
    const float* Wm    = (const float*)d_in[1];
    const float* bm    = (const float*)d_in[2];
    const float* Wu    = (const float*)d_in[3];
    const float* bu    = (const float*)d_in[4];
    const float* gamma = (const float*)d_in[5];
    const float* beta  = (const float*)d_in[6];
    const int*   src   = (const int*)d_in[7];
    const int*   dst   = (const int*)d_in[8];

    int n = in_sizes[0] / 64;
    int e = in_sizes[7];
    int npad = ((n + 127) / 128) * 128;
    float* z = (float*)d_out;

    char* w = (char*)d_ws;
    size_t off = 0;
    auto take = [&](size_t bytes) -> void* {
        void* p = w + off;
        off = (off + bytes + 255) & ~(size_t)255;
        return p;
    };
    unsigned* Ab   = (unsigned*)take((size_t)npad * 32 * sizeof(unsigned));
    float*    B    = (float*)take((size_t)n * 64 * sizeof(float));
    unsigned* xbu  = (unsigned*)take((size_t)npad * 32 * sizeof(unsigned));
    unsigned* hbu  = (unsigned*)take((size_t)npad * 128 * sizeof(unsigned));
    float*    s1   = (float*)take((size_t)npad * sizeof(float));
    float*    s2   = (float*)take((size_t)npad * sizeof(float));
    short*    Wup  = (short*)take((size_t)26 * 4 * 64 * 8 * sizeof(short));
    int*      deg  = (int*)take((size_t)n * sizeof(int));
    int*      offs = (int*)take((size_t)(n + 1) * sizeof(int));
    int*      cursor = (int*)take((size_t)n * sizeof(int));
    int*      csr  = (int*)take((size_t)e * sizeof(int));
    float*    bnacc = (float*)take(128 * sizeof(float));
    int*      bsum = (int*)take(64 * sizeof(int));
    int*      boff = (int*)take(64 * sizeof(int));

    (void)n_in; (void)out_size; (void)ws_size;

    hipMemsetAsync(deg, 0, (size_t)n * sizeof(int), stream);
    hipMemsetAsync(bnacc, 0, 128 * sizeof(float), stream);

    int nb_rows64 = npad / 64;
    int nb_edge = (e + 255) / 256;
    int nb_scan = (n + 1023) / 1024;

    repack_wu<<<26, 256, 0, stream>>>(Wu, Wup);
    proj_ab<<<nb_rows64, 256, 0, stream>>>(x, Wm, Ab, B, xbu, n);
    count_deg<<<(e / 4 + 255) / 256, 256, 0, stream>>>(dst, deg, e);
    scan_block<<<nb_scan, 256, 0, stream>>>(deg, offs, bsum, n);
    scan_carry<<<1, 64, 0, stream>>>(bsum, boff, nb_scan, offs, n);
    scan_apply<<<(n + 255) / 256, 256, 0, stream>>>(offs, cursor, boff, n);
    fill_csr<<<nb_edge, 256, 0, stream>>>(src, dst, cursor, csr, e);
    node_reduce<<<(npad + 3) / 4, 256, 0, stream>>>(Ab, B, bm, offs, csr, hbu, s1, s2, n, npad);

    float snorm = (float)(1.0 / sqrt((double)n));
    gemm_mfma<<<npad / 128, 256, 0, stream>>>((const short*)xbu, (const short*)hbu,
                                              s1, s2, Wup, bu, z, n, snorm);

    bn_stats<<<512, 256, 0, stream>>>(z, bnacc, n);
    bn_apply<<<1024, 256, 0, stream>>>(z, bnacc, gamma, beta, n);
}

// Round 4
// 152.526 us; speedup vs baseline: 2.6285x; 1.3456x over previous
//
#include <hip/hip_runtime.h>
#include <hip/hip_bf16.h>

// PNAConvTower: h' = BN( snorm * ([x, PNA_aggr(x)] @ Wu + bu) )
// msg[e] = A[src[e]] + B[dst[e]] + bm   where A = x@Wm[:64], B = x@Wm[64:]
// Stats are shift-invariant: reduce over A[src] only, add (B[dst]+bm) at the end.
// CSR built via 2-level counting sort (bucket = dst>>7) to avoid scatter
// write-amplification (R3: fill_csr wrote 52MB HBM for a 3.2MB array).
// z = x@W0 + h@W1 + s1*(h@W2) + s2*(h@W3) + bu  (scalers folded, bf16 MFMA)

#define DELTA_C 2.83f
#define BN_EPS_C 1e-5f
#define MOM_EPS_C 1e-30f
#define FLT_BIG 3.402823466e38f
#define BSHIFT 7            // 128 nodes per bucket
#define NBMAX 512           // supports n <= 65536

typedef __attribute__((ext_vector_type(8))) short bf16x8;   // 8 bf16 (4 VGPRs)
typedef __attribute__((ext_vector_type(4))) float f32x4;    // MFMA C/D frag

static __device__ __forceinline__ unsigned short f2bf(float f) {
    unsigned u = __float_as_uint(f);
    unsigned r = (u + 0x7FFFu + ((u >> 16) & 1u)) >> 16;    // RNE
    return (unsigned short)r;
}
static __device__ __forceinline__ unsigned pack2(float a, float b) {
    return (unsigned)f2bf(a) | ((unsigned)f2bf(b) << 16);
}
static __device__ __forceinline__ float bflo(unsigned u) { return __uint_as_float(u << 16); }
static __device__ __forceinline__ float bfhi(unsigned u) { return __uint_as_float(u & 0xFFFF0000u); }

// ---------------- K0: repack Wu (832x64 f32) into bf16 fragment order -------
// Wup layout: [chunk(26)][cfrag(4)][lane(64)][i(8)]
//   k_global = chunk*32 + (lane>>4)*8 + i ; col = cfrag*16 + (lane&15)
__global__ __launch_bounds__(256) void repack_wu(
    const float* __restrict__ Wu, short* __restrict__ Wup)
{
    int idx = blockIdx.x * 256 + threadIdx.x;
    if (idx >= 26 * 4 * 64) return;
    int lane = idx & 63, c = (idx >> 6) & 3, kc = idx >> 8;
    int kbase = kc * 32 + (lane >> 4) * 8;
    int col = c * 16 + (lane & 15);
    unsigned short o[8];
    #pragma unroll
    for (int i = 0; i < 8; ++i)
        o[i] = f2bf(Wu[(size_t)(kbase + i) * 64 + col]);
    uint4 u;
    u.x = o[0] | ((unsigned)o[1] << 16);
    u.y = o[2] | ((unsigned)o[3] << 16);
    u.z = o[4] | ((unsigned)o[5] << 16);
    u.w = o[6] | ((unsigned)o[7] << 16);
    *(uint4*)(Wup + (size_t)idx * 8) = u;
}

// ---------------- K1: A(bf16) = x@Wm_top, B(f32) = x@Wm_bot, xb = bf16(x) ---
__global__ __launch_bounds__(256) void proj_ab(
    const float* __restrict__ x, const float* __restrict__ Wm,
    unsigned* __restrict__ Ab, float* __restrict__ B,
    unsigned* __restrict__ xbu, int n)
{
    __shared__ float wm[128][68];
    __shared__ float xs[64][68];
    int t = threadIdx.x;
    for (int i = t; i < 2048; i += 256) {
        int k = i >> 4, c4 = (i & 15) << 2;
        *(float4*)&wm[k][c4] = *(const float4*)&Wm[k * 64 + c4];
    }
    int row0 = blockIdx.x * 64;
    for (int i = t; i < 1024; i += 256) {
        int r = i >> 4, k4 = (i & 15) << 2;
        int row = row0 + r;
        float4 v = make_float4(0.f, 0.f, 0.f, 0.f);
        if (row < n) v = *(const float4*)&x[(size_t)row * 64 + k4];
        *(float4*)&xs[r][k4] = v;
    }
    __syncthreads();
    int tr = t >> 4, tc = t & 15, c0 = tc << 2;
    float a[4][4] = {}; float b[4][4] = {};
    #pragma unroll 8
    for (int k = 0; k < 64; ++k) {
        float4 wa = *(float4*)&wm[k][c0];
        float4 wb = *(float4*)&wm[64 + k][c0];
        #pragma unroll
        for (int i = 0; i < 4; ++i) {
            float xv = xs[tr * 4 + i][k];
            a[i][0] += xv * wa.x; a[i][1] += xv * wa.y; a[i][2] += xv * wa.z; a[i][3] += xv * wa.w;
            b[i][0] += xv * wb.x; b[i][1] += xv * wb.y; b[i][2] += xv * wb.z; b[i][3] += xv * wb.w;
        }
    }
    #pragma unroll
    for (int i = 0; i < 4; ++i) {
        int r = tr * 4 + i;
        int row = row0 + r;
        uint2 xp;
        xp.x = pack2(xs[r][c0], xs[r][c0 + 1]);
        xp.y = pack2(xs[r][c0 + 2], xs[r][c0 + 3]);
        *(uint2*)&xbu[(size_t)row * 32 + (c0 >> 1)] = xp;
        if (row < n) {
            uint2 ap;
            ap.x = pack2(a[i][0], a[i][1]);
            ap.y = pack2(a[i][2], a[i][3]);
            *(uint2*)&Ab[(size_t)row * 32 + (c0 >> 1)] = ap;
            *(float4*)&B[(size_t)row * 64 + c0] = make_float4(b[i][0], b[i][1], b[i][2], b[i][3]);
        }
    }
}

// ---------------- K2a: bucket histogram ------------------------------------
__global__ __launch_bounds__(256) void bin_count(
    const int* __restrict__ dst, int* __restrict__ bcnt, int e)
{
    __shared__ int h[NBMAX];
    int t = threadIdx.x;
    for (int b = t; b < NBMAX; b += 256) h[b] = 0;
    __syncthreads();
    int base = blockIdx.x * 4096;
    int cnt = min(4096, e - base);
    for (int i = t; i < cnt; i += 256)
        atomicAdd(&h[dst[base + i] >> BSHIFT], 1);
    __syncthreads();
    for (int b = t; b < NBMAX; b += 256)
        if (h[b]) atomicAdd(&bcnt[b], h[b]);
}

// ---------------- K2b: bucket prefix (1 wave, 8/lane over 512) --------------
__global__ void bin_scan(const int* __restrict__ bcnt, int* __restrict__ boff,
                         int* __restrict__ gcur, int nb,
                         int* __restrict__ offs, int n, int e)
{
    int t = threadIdx.x;   // 64 threads
    int v[8]; int s = 0;
    #pragma unroll
    for (int j = 0; j < 8; ++j) {
        int b = t * 8 + j;
        v[j] = (b < nb) ? bcnt[b] : 0;
        s += v[j];
    }
    int inc = s;
    #pragma unroll
    for (int st = 1; st < 64; st <<= 1) {
        int u = __shfl_up(inc, st);
        if (t >= st) inc += u;
    }
    int ex = inc - s;
    #pragma unroll
    for (int j = 0; j < 8; ++j) {
        int b = t * 8 + j;
        if (b < nb) { boff[b] = ex; gcur[b] = ex; }
        ex += v[j];
    }
    if (t == 63) { boff[nb] = e; offs[n] = e; }
}

// ---------------- K2c: bucket-major edge reorder ----------------------------
// 4096 edges/block; LDS reorder -> contiguous ~84B bursts per bucket segment
__global__ __launch_bounds__(256) void bin_scatter(
    const int* __restrict__ src, const int* __restrict__ dst,
    int* __restrict__ gcur, int2* __restrict__ pairs_out, int e)
{
    __shared__ int hcnt[NBMAX], hstart[NBMAX], hcur[NBMAX], gpos[NBMAX];
    __shared__ int2 pairs[4096];
    int t = threadIdx.x;
    int base = blockIdx.x * 4096;
    int cnt = min(4096, e - base);
    for (int b = t; b < NBMAX; b += 256) hcnt[b] = 0;
    __syncthreads();

    int ls[16], ld[16];                       // static-indexed (regs, not scratch)
    #pragma unroll
    for (int j = 0; j < 16; ++j) {
        int i = t + j * 256;
        ls[j] = 0; ld[j] = -1;
        if (i < cnt) {
            ls[j] = src[base + i];
            ld[j] = dst[base + i];
            atomicAdd(&hcnt[ld[j] >> BSHIFT], 1);
        }
    }
    __syncthreads();
    if (t < 64) {                             // exclusive prefix over 512 buckets
        int v[8]; int s = 0;
        #pragma unroll
        for (int j = 0; j < 8; ++j) { v[j] = hcnt[t * 8 + j]; s += v[j]; }
        int inc = s;
        #pragma unroll
        for (int st = 1; st < 64; st <<= 1) {
            int u = __shfl_up(inc, st);
            if (t >= st) inc += u;
        }
        int ex = inc - s;
        #pragma unroll
        for (int j = 0; j < 8; ++j) {
            hstart[t * 8 + j] = ex;
            hcur[t * 8 + j] = ex;
            ex += v[j];
        }
    }
    __syncthreads();
    #pragma unroll
    for (int j = 0; j < 16; ++j) {
        if (ld[j] >= 0) {
            int pos = atomicAdd(&hcur[ld[j] >> BSHIFT], 1);
            pairs[pos] = make_int2(ls[j], ld[j]);
        }
    }
    __syncthreads();
    for (int b = t; b < NBMAX; b += 256) {    // one global atomic per (block,bucket)
        int c = hcnt[b];
        if (c) gpos[b] = atomicAdd(&gcur[b], c);
    }
    __syncthreads();
    #pragma unroll
    for (int j = 0; j < 16; ++j) {
        int i = t + j * 256;
        if (i < cnt) {
            int2 p = pairs[i];
            int b = p.y >> BSHIFT;
            pairs_out[gpos[b] + (i - hstart[b])] = p;
        }
    }
}

// ---------------- K2d: per-bucket CSR fill + offs ---------------------------
// 1 block / bucket; csr segment (~8KB) stays hot in one XCD's L2 -> full-line WB
__global__ __launch_bounds__(128) void csr_fill(
    const int2* __restrict__ pairs, const int* __restrict__ boff,
    int* __restrict__ offs, int* __restrict__ csr, int n)
{
    __shared__ int hist[128], pref[128], cur[128];
    int b = blockIdx.x, t = threadIdx.x;
    int base = boff[b], cnt = boff[b + 1] - base;
    int node0 = b << BSHIFT;
    hist[t] = 0;
    __syncthreads();
    for (int i = t; i < cnt; i += 128)
        atomicAdd(&hist[pairs[base + i].y & 127], 1);
    __syncthreads();
    if (t < 64) {
        int v0 = hist[2 * t], v1 = hist[2 * t + 1];
        int s = v0 + v1, inc = s;
        #pragma unroll
        for (int st = 1; st < 64; st <<= 1) {
            int u = __shfl_up(inc, st);
            if (t >= st) inc += u;
        }
        int ex = inc - s;
        pref[2 * t] = ex;       cur[2 * t] = ex;
        pref[2 * t + 1] = ex + v0; cur[2 * t + 1] = ex + v0;
    }
    __syncthreads();
    int node = node0 + t;
    if (node < n) offs[node] = base + pref[t];
    for (int i = t; i < cnt; i += 128) {
        int2 p = pairs[base + i];
        int pos = atomicAdd(&cur[p.y & 127], 1);
        csr[base + pos] = p.x;
    }
}

// ---------------- K5: per-node multi-stat reduction (1 wave / node) ---------
// bf16 A rows (128B): half-wave per edge -> 2 edges per load instruction.
__global__ __launch_bounds__(256) void node_reduce(
    const unsigned* __restrict__ Ab, const float* __restrict__ Bp,
    const float* __restrict__ bm,
    const int* __restrict__ offs, const int* __restrict__ csr,
    unsigned* __restrict__ hbu, float* __restrict__ s1, float* __restrict__ s2,
    int n, int npad)
{
    int wid = threadIdx.x >> 6;
    int lane = threadIdx.x & 63;
    int node = blockIdx.x * 4 + wid;
    if (node >= npad) return;
    unsigned* hrow = hbu + (size_t)node * 128;   // 256 bf16 = 128 uints
    int l32 = lane & 31;
    int half = lane >> 5;
    int beg = 0, dg = 0;
    if (node < n) { beg = offs[node]; dg = offs[node + 1] - beg; }
    if (dg == 0) {
        if (half == 0) {
            hrow[l32] = 0u; hrow[32 + l32] = 0u; hrow[64 + l32] = 0u; hrow[96 + l32] = 0u;
        }
        if (lane == 0) { s1[node] = 0.f; s2[node] = 0.f; }
        return;
    }

    float s0 = 0.f, s1a = 0.f, ss0 = 0.f, ss1 = 0.f;
    float mx0 = -FLT_BIG, mx1 = -FLT_BIG, mn0 = FLT_BIG, mn1 = FLT_BIG;

#define ACC(u) { float v0 = bflo(u), v1 = bfhi(u);                          \
    s0 += v0; s1a += v1;                                                    \
    ss0 = fmaf(v0, v0, ss0); ss1 = fmaf(v1, v1, ss1);                       \
    mx0 = fmaxf(mx0, v0); mx1 = fmaxf(mx1, v1);                             \
    mn0 = fminf(mn0, v0); mn1 = fminf(mn1, v1); }

    int j = beg, end = beg + dg;
    for (; j + 3 < end; j += 4) {           // 4 edges, 2 independent gathers
        int i0 = csr[j], i1 = csr[j + 1], i2 = csr[j + 2], i3 = csr[j + 3];
        int sa = half ? i1 : i0;
        int sb = half ? i3 : i2;
        unsigned ua = Ab[(size_t)sa * 32 + l32];
        unsigned ub = Ab[(size_t)sb * 32 + l32];
        ACC(ua); ACC(ub);
    }
    for (; j + 1 < end; j += 2) {
        int i0 = csr[j], i1 = csr[j + 1];
        int sa = half ? i1 : i0;
        unsigned ua = Ab[(size_t)sa * 32 + l32];
        ACC(ua);
    }
    if (j < end) {                          // odd tail: half 0 only
        int sa = csr[j];
        unsigned ua = Ab[(size_t)sa * 32 + l32];
        if (half == 0) ACC(ua);
    }
#undef ACC

    s0 += __shfl_xor(s0, 32);  s1a += __shfl_xor(s1a, 32);
    ss0 += __shfl_xor(ss0, 32); ss1 += __shfl_xor(ss1, 32);
    mx0 = fmaxf(mx0, __shfl_xor(mx0, 32)); mx1 = fmaxf(mx1, __shfl_xor(mx1, 32));
    mn0 = fminf(mn0, __shfl_xor(mn0, 32)); mn1 = fminf(mn1, __shfl_xor(mn1, 32));

    float fd = (float)dg, inv = 1.0f / fd;
    float2 bv = *(const float2*)(Bp + (size_t)node * 64 + 2 * l32);
    float2 bmv = *(const float2*)(bm + 2 * l32);
    float bn0 = bv.x + bmv.x, bn1 = bv.y + bmv.y;
    float ma0 = s0 * inv, ma1 = s1a * inv;
    float var0 = ss0 * inv - ma0 * ma0; if (var0 < 0.f) var0 = 0.f;
    float var1 = ss1 * inv - ma1 * ma1; if (var1 < 0.f) var1 = 0.f;
    float sd0 = sqrtf(var0 + MOM_EPS_C), sd1 = sqrtf(var1 + MOM_EPS_C);

    if (half == 0) {
        hrow[l32]      = pack2(ma0 + bn0, ma1 + bn1);
        hrow[32 + l32] = pack2(mx0 + bn0, mx1 + bn1);
        hrow[64 + l32] = pack2(mn0 + bn0, mn1 + bn1);
        hrow[96 + l32] = pack2(sd0, sd1);
    }
    if (lane == 0) {
        float logD = logf(fd + 1.0f);
        s1[node] = logD / DELTA_C;
        s2[node] = DELTA_C / logD;
    }
}

// ---------------- K6: MFMA update GEMM -------------------------------------
__global__ __launch_bounds__(256) void gemm_mfma(
    const short* __restrict__ xb, const short* __restrict__ hb,
    const float* __restrict__ s1p, const float* __restrict__ s2p,
    const short* __restrict__ Wup, const float* __restrict__ bu,
    float* __restrict__ z, int n, float snorm)
{
    int t = threadIdx.x;
    int lane = t & 63, w = t >> 6;
    int rb = blockIdx.x * 128 + w * 32;
    int r16 = lane & 15, kg = lane >> 4;

    f32x4 accx[2][4] = {};
    f32x4 acc1[2][4] = {};
    f32x4 acc2[2][4] = {};
    f32x4 acc3[2][4] = {};

    const short* xr0 = xb + (size_t)(rb + r16) * 64 + kg * 8;
    const short* xr1 = xr0 + 16 * 64;

    #pragma unroll
    for (int kc = 0; kc < 2; ++kc) {
        bf16x8 a0 = *(const bf16x8*)(xr0 + kc * 32);
        bf16x8 a1 = *(const bf16x8*)(xr1 + kc * 32);
        #pragma unroll
        for (int c = 0; c < 4; ++c) {
            bf16x8 b = *(const bf16x8*)(Wup + (size_t)((kc * 4 + c) * 64 + lane) * 8);
            accx[0][c] = __builtin_amdgcn_mfma_f32_16x16x32_bf16(a0, b, accx[0][c], 0, 0, 0);
            accx[1][c] = __builtin_amdgcn_mfma_f32_16x16x32_bf16(a1, b, accx[1][c], 0, 0, 0);
        }
    }

    const short* hr0 = hb + (size_t)(rb + r16) * 256 + kg * 8;
    const short* hr1 = hr0 + 16 * 256;

    #pragma unroll 1
    for (int kh = 0; kh < 8; ++kh) {
        bf16x8 a0 = *(const bf16x8*)(hr0 + kh * 32);
        bf16x8 a1 = *(const bf16x8*)(hr1 + kh * 32);
        #pragma unroll
        for (int c = 0; c < 4; ++c) {
            bf16x8 b1 = *(const bf16x8*)(Wup + (size_t)(((2  + kh) * 4 + c) * 64 + lane) * 8);
            bf16x8 b2 = *(const bf16x8*)(Wup + (size_t)(((10 + kh) * 4 + c) * 64 + lane) * 8);
            bf16x8 b3 = *(const bf16x8*)(Wup + (size_t)(((18 + kh) * 4 + c) * 64 + lane) * 8);
            acc1[0][c] = __builtin_amdgcn_mfma_f32_16x16x32_bf16(a0, b1, acc1[0][c], 0, 0, 0);
            acc1[1][c] = __builtin_amdgcn_mfma_f32_16x16x32_bf16(a1, b1, acc1[1][c], 0, 0, 0);
            acc2[0][c] = __builtin_amdgcn_mfma_f32_16x16x32_bf16(a0, b2, acc2[0][c], 0, 0, 0);
            acc2[1][c] = __builtin_amdgcn_mfma_f32_16x16x32_bf16(a1, b2, acc2[1][c], 0, 0, 0);
            acc3[0][c] = __builtin_amdgcn_mfma_f32_16x16x32_bf16(a0, b3, acc3[0][c], 0, 0, 0);
            acc3[1][c] = __builtin_amdgcn_mfma_f32_16x16x32_bf16(a1, b3, acc3[1][c], 0, 0, 0);
        }
    }

    #pragma unroll
    for (int s = 0; s < 2; ++s) {
        int r0 = rb + s * 16 + kg * 4;
        float s1v[4], s2v[4];
        #pragma unroll
        for (int r = 0; r < 4; ++r) { s1v[r] = s1p[r0 + r]; s2v[r] = s2p[r0 + r]; }
        #pragma unroll
        for (int c = 0; c < 4; ++c) {
            int col = c * 16 + r16;
            float bval = bu[col];
            #pragma unroll
            for (int r = 0; r < 4; ++r) {
                int row = r0 + r;
                if (row < n) {
                    float v = accx[s][c][r] + acc1[s][c][r]
                            + s1v[r] * acc2[s][c][r] + s2v[r] * acc3[s][c][r] + bval;
                    z[(size_t)row * 64 + col] = v * snorm;
                }
            }
        }
    }
}

// ---------------- K7: BN column stats --------------------------------------
__global__ __launch_bounds__(256) void bn_stats(
    const float* __restrict__ z, float* __restrict__ acc, int n)
{
    int t = threadIdx.x;
    int c = t & 63, rg = t >> 6;
    float s = 0.f, ss = 0.f;
    for (int r = blockIdx.x * 4 + rg; r < n; r += gridDim.x * 4) {
        float v = z[(size_t)r * 64 + c];
        s += v; ss += v * v;
    }
    __shared__ float sb[256], ssb[256];
    sb[t] = s; ssb[t] = ss;
    __syncthreads();
    if (t < 128) { sb[t] += sb[t + 128]; ssb[t] += ssb[t + 128]; }
    __syncthreads();
    if (t < 64) {
        atomicAdd(&acc[c], sb[t] + sb[t + 64]);
        atomicAdd(&acc[64 + c], ssb[t] + ssb[t + 64]);
    }
}

// ---------------- K8: BN normalize (in place on d_out) ----------------------
__global__ __launch_bounds__(256) void bn_apply(
    float* __restrict__ z, const float* __restrict__ acc,
    const float* __restrict__ gamma, const float* __restrict__ beta, int n)
{
    float inv_n = 1.0f / (float)n;
    int total = n * 64;
    for (int i = blockIdx.x * blockDim.x + threadIdx.x; i < total; i += gridDim.x * blockDim.x) {
        int c = i & 63;
        float mu = acc[c] * inv_n;
        float var = acc[64 + c] * inv_n - mu * mu;
        if (var < 0.f) var = 0.f;
        float inv = rsqrtf(var + BN_EPS_C);
        z[i] = (z[i] - mu) * inv * gamma[c] + beta[c];
    }
}

extern "C" void kernel_launch(void* const* d_in, const int* in_sizes, int n_in,
                              void* d_out, int out_size, void* d_ws, size_t ws_size,
                              hipStream_t stream)
{
    const float* x     = (const float*)d_in[0];
    const float* Wm    = (const float*)d_in[1];
    const float* bm    = (const float*)d_in[2];
    const float* Wu    = (const float*)d_in[3];
    const float* bu    = (const float*)d_in[4];
    const float* gamma = (const float*)d_in[5];
    const float* beta  = (const float*)d_in[6];
    const int*   src   = (const int*)d_in[7];
    const int*   dst   = (const int*)d_in[8];

    int n = in_sizes[0] / 64;
    int e = in_sizes[7];
    int npad = ((n + 127) / 128) * 128;
    int nb = (n + 127) >> BSHIFT;          // buckets (<=512 for n<=65536)
    float* z = (float*)d_out;

    char* w = (char*)d_ws;
    size_t off = 0;
    auto take = [&](size_t bytes) -> void* {
        void* p = w + off;
        off = (off + bytes + 255) & ~(size_t)255;
        return p;
    };
    unsigned* Ab    = (unsigned*)take((size_t)npad * 32 * sizeof(unsigned));
    float*    B     = (float*)take((size_t)n * 64 * sizeof(float));
    unsigned* xbu   = (unsigned*)take((size_t)npad * 32 * sizeof(unsigned));
    unsigned* hbu   = (unsigned*)take((size_t)npad * 128 * sizeof(unsigned));
    float*    s1    = (float*)take((size_t)npad * sizeof(float));
    float*    s2    = (float*)take((size_t)npad * sizeof(float));
    short*    Wup   = (short*)take((size_t)26 * 4 * 64 * 8 * sizeof(short));
    int*      offs  = (int*)take((size_t)(n + 1) * sizeof(int));
    int*      csr   = (int*)take((size_t)e * sizeof(int));
    int2*     prs   = (int2*)take((size_t)e * sizeof(int2));
    int*      bcnt  = (int*)take((size_t)NBMAX * sizeof(int));
    int*      boff  = (int*)take((size_t)(NBMAX + 1) * sizeof(int));
    int*      gcur  = (int*)take((size_t)NBMAX * sizeof(int));
    float*    bnacc = (float*)take(128 * sizeof(float));

    (void)n_in; (void)out_size; (void)ws_size;

    hipMemsetAsync(bcnt, 0, (size_t)NBMAX * sizeof(int), stream);
    hipMemsetAsync(bnacc, 0, 128 * sizeof(float), stream);

    int nb_rows64 = npad / 64;
    int nb_chunk = (e + 4095) / 4096;

    repack_wu<<<26, 256, 0, stream>>>(Wu, Wup);
    proj_ab<<<nb_rows64, 256, 0, stream>>>(x, Wm, Ab, B, xbu, n);
    bin_count<<<nb_chunk, 256, 0, stream>>>(dst, bcnt, e);
    bin_scan<<<1, 64, 0, stream>>>(bcnt, boff, gcur, nb, offs, n, e);
    bin_scatter<<<nb_chunk, 256, 0, stream>>>(src, dst, gcur, prs, e);
    csr_fill<<<nb, 128, 0, stream>>>(prs, boff, offs, csr, n);
    node_reduce<<<(npad + 3) / 4, 256, 0, stream>>>(Ab, B, bm, offs, csr, hbu, s1, s2, n, npad);

    float snorm = (float)(1.0 / sqrt((double)n));
    gemm_mfma<<<npad / 128, 256, 0, stream>>>((const short*)xbu, (const short*)hbu,
                                              s1, s2, Wup, bu, z, n, snorm);

    bn_stats<<<512, 256, 0, stream>>>(z, bnacc, n);
    bn_apply<<<1024, 256, 0, stream>>>(z, bnacc, gamma, beta, n);
}

// Round 5
// 132.375 us; speedup vs baseline: 3.0286x; 1.1522x over previous
//
#include <hip/hip_runtime.h>
#include <hip/hip_bf16.h>

// PNAConvTower: h' = BN( snorm * ([x, PNA_aggr(x)] @ Wu + bu) )
// msg[e] = A[src[e]] + B[dst[e]] + bm   where A = x@Wm[:64], B = x@Wm[64:]
// Stats are shift-invariant: reduce over A[src] only, add (B[dst]+bm) at the end.
// CSR built via 2-level counting sort (bucket = dst>>7) to avoid scatter
// write-amplification (R3: fill_csr wrote 52MB HBM for a 3.2MB array).
// z = x@W0 + h@W1 + s1*(h@W2) + s2*(h@W3) + bu  (scalers folded, bf16 MFMA)
// R5: BN column stats fused into the GEMM epilogue; no memsets in-graph.

#define DELTA_C 2.83f
#define BN_EPS_C 1e-5f
#define MOM_EPS_C 1e-30f
#define FLT_BIG 3.402823466e38f
#define BSHIFT 7            // 128 nodes per bucket
#define NBMAX 512           // supports n <= 65536

typedef __attribute__((ext_vector_type(8))) short bf16x8;   // 8 bf16 (4 VGPRs)
typedef __attribute__((ext_vector_type(4))) float f32x4;    // MFMA C/D frag

static __device__ __forceinline__ unsigned short f2bf(float f) {
    unsigned u = __float_as_uint(f);
    unsigned r = (u + 0x7FFFu + ((u >> 16) & 1u)) >> 16;    // RNE
    return (unsigned short)r;
}
static __device__ __forceinline__ unsigned pack2(float a, float b) {
    return (unsigned)f2bf(a) | ((unsigned)f2bf(b) << 16);
}
static __device__ __forceinline__ float bflo(unsigned u) { return __uint_as_float(u << 16); }
static __device__ __forceinline__ float bfhi(unsigned u) { return __uint_as_float(u & 0xFFFF0000u); }

// ---------------- K-1: zero the tiny accumulators (replaces 2 memsets) ------
__global__ __launch_bounds__(512) void init_small(
    int* __restrict__ bcnt, float* __restrict__ bnacc)
{
    int t = threadIdx.x;
    if (t < NBMAX) bcnt[t] = 0;
    if (t < 128) bnacc[t] = 0.f;
}

// ---------------- K0: repack Wu (832x64 f32) into bf16 fragment order -------
// Wup layout: [chunk(26)][cfrag(4)][lane(64)][i(8)]
//   k_global = chunk*32 + (lane>>4)*8 + i ; col = cfrag*16 + (lane&15)
__global__ __launch_bounds__(256) void repack_wu(
    const float* __restrict__ Wu, short* __restrict__ Wup)
{
    int idx = blockIdx.x * 256 + threadIdx.x;
    if (idx >= 26 * 4 * 64) return;
    int lane = idx & 63, c = (idx >> 6) & 3, kc = idx >> 8;
    int kbase = kc * 32 + (lane >> 4) * 8;
    int col = c * 16 + (lane & 15);
    unsigned short o[8];
    #pragma unroll
    for (int i = 0; i < 8; ++i)
        o[i] = f2bf(Wu[(size_t)(kbase + i) * 64 + col]);
    uint4 u;
    u.x = o[0] | ((unsigned)o[1] << 16);
    u.y = o[2] | ((unsigned)o[3] << 16);
    u.z = o[4] | ((unsigned)o[5] << 16);
    u.w = o[6] | ((unsigned)o[7] << 16);
    *(uint4*)(Wup + (size_t)idx * 8) = u;
}

// ---------------- K1: A(bf16) = x@Wm_top, B(f32) = x@Wm_bot, xb = bf16(x) ---
__global__ __launch_bounds__(256) void proj_ab(
    const float* __restrict__ x, const float* __restrict__ Wm,
    unsigned* __restrict__ Ab, float* __restrict__ B,
    unsigned* __restrict__ xbu, int n)
{
    __shared__ float wm[128][68];
    __shared__ float xs[64][68];
    int t = threadIdx.x;
    for (int i = t; i < 2048; i += 256) {
        int k = i >> 4, c4 = (i & 15) << 2;
        *(float4*)&wm[k][c4] = *(const float4*)&Wm[k * 64 + c4];
    }
    int row0 = blockIdx.x * 64;
    for (int i = t; i < 1024; i += 256) {
        int r = i >> 4, k4 = (i & 15) << 2;
        int row = row0 + r;
        float4 v = make_float4(0.f, 0.f, 0.f, 0.f);
        if (row < n) v = *(const float4*)&x[(size_t)row * 64 + k4];
        *(float4*)&xs[r][k4] = v;
    }
    __syncthreads();
    int tr = t >> 4, tc = t & 15, c0 = tc << 2;
    float a[4][4] = {}; float b[4][4] = {};
    #pragma unroll 8
    for (int k = 0; k < 64; ++k) {
        float4 wa = *(float4*)&wm[k][c0];
        float4 wb = *(float4*)&wm[64 + k][c0];
        #pragma unroll
        for (int i = 0; i < 4; ++i) {
            float xv = xs[tr * 4 + i][k];
            a[i][0] += xv * wa.x; a[i][1] += xv * wa.y; a[i][2] += xv * wa.z; a[i][3] += xv * wa.w;
            b[i][0] += xv * wb.x; b[i][1] += xv * wb.y; b[i][2] += xv * wb.z; b[i][3] += xv * wb.w;
        }
    }
    #pragma unroll
    for (int i = 0; i < 4; ++i) {
        int r = tr * 4 + i;
        int row = row0 + r;
        uint2 xp;
        xp.x = pack2(xs[r][c0], xs[r][c0 + 1]);
        xp.y = pack2(xs[r][c0 + 2], xs[r][c0 + 3]);
        *(uint2*)&xbu[(size_t)row * 32 + (c0 >> 1)] = xp;
        if (row < n) {
            uint2 ap;
            ap.x = pack2(a[i][0], a[i][1]);
            ap.y = pack2(a[i][2], a[i][3]);
            *(uint2*)&Ab[(size_t)row * 32 + (c0 >> 1)] = ap;
            *(float4*)&B[(size_t)row * 64 + c0] = make_float4(b[i][0], b[i][1], b[i][2], b[i][3]);
        }
    }
}

// ---------------- K2a: bucket histogram ------------------------------------
__global__ __launch_bounds__(256) void bin_count(
    const int* __restrict__ dst, int* __restrict__ bcnt, int e)
{
    __shared__ int h[NBMAX];
    int t = threadIdx.x;
    for (int b = t; b < NBMAX; b += 256) h[b] = 0;
    __syncthreads();
    int base = blockIdx.x * 4096;
    int cnt = min(4096, e - base);
    for (int i = t; i < cnt; i += 256)
        atomicAdd(&h[dst[base + i] >> BSHIFT], 1);
    __syncthreads();
    for (int b = t; b < NBMAX; b += 256)
        if (h[b]) atomicAdd(&bcnt[b], h[b]);
}

// ---------------- K2b: bucket prefix (1 wave, 8/lane over 512) --------------
__global__ void bin_scan(const int* __restrict__ bcnt, int* __restrict__ boff,
                         int* __restrict__ gcur, int nb,
                         int* __restrict__ offs, int n, int e)
{
    int t = threadIdx.x;   // 64 threads
    int v[8]; int s = 0;
    #pragma unroll
    for (int j = 0; j < 8; ++j) {
        int b = t * 8 + j;
        v[j] = (b < nb) ? bcnt[b] : 0;
        s += v[j];
    }
    int inc = s;
    #pragma unroll
    for (int st = 1; st < 64; st <<= 1) {
        int u = __shfl_up(inc, st);
        if (t >= st) inc += u;
    }
    int ex = inc - s;
    #pragma unroll
    for (int j = 0; j < 8; ++j) {
        int b = t * 8 + j;
        if (b < nb) { boff[b] = ex; gcur[b] = ex; }
        ex += v[j];
    }
    if (t == 63) { boff[nb] = e; offs[n] = e; }
}

// ---------------- K2c: bucket-major edge reorder ----------------------------
__global__ __launch_bounds__(256) void bin_scatter(
    const int* __restrict__ src, const int* __restrict__ dst,
    int* __restrict__ gcur, int2* __restrict__ pairs_out, int e)
{
    __shared__ int hcnt[NBMAX], hstart[NBMAX], hcur[NBMAX], gpos[NBMAX];
    __shared__ int2 pairs[4096];
    int t = threadIdx.x;
    int base = blockIdx.x * 4096;
    int cnt = min(4096, e - base);
    for (int b = t; b < NBMAX; b += 256) hcnt[b] = 0;
    __syncthreads();

    int ls[16], ld[16];                       // static-indexed (regs, not scratch)
    #pragma unroll
    for (int j = 0; j < 16; ++j) {
        int i = t + j * 256;
        ls[j] = 0; ld[j] = -1;
        if (i < cnt) {
            ls[j] = src[base + i];
            ld[j] = dst[base + i];
            atomicAdd(&hcnt[ld[j] >> BSHIFT], 1);
        }
    }
    __syncthreads();
    if (t < 64) {                             // exclusive prefix over 512 buckets
        int v[8]; int s = 0;
        #pragma unroll
        for (int j = 0; j < 8; ++j) { v[j] = hcnt[t * 8 + j]; s += v[j]; }
        int inc = s;
        #pragma unroll
        for (int st = 1; st < 64; st <<= 1) {
            int u = __shfl_up(inc, st);
            if (t >= st) inc += u;
        }
        int ex = inc - s;
        #pragma unroll
        for (int j = 0; j < 8; ++j) {
            hstart[t * 8 + j] = ex;
            hcur[t * 8 + j] = ex;
            ex += v[j];
        }
    }
    __syncthreads();
    #pragma unroll
    for (int j = 0; j < 16; ++j) {
        if (ld[j] >= 0) {
            int pos = atomicAdd(&hcur[ld[j] >> BSHIFT], 1);
            pairs[pos] = make_int2(ls[j], ld[j]);
        }
    }
    __syncthreads();
    for (int b = t; b < NBMAX; b += 256) {    // one global atomic per (block,bucket)
        int c = hcnt[b];
        if (c) gpos[b] = atomicAdd(&gcur[b], c);
    }
    __syncthreads();
    #pragma unroll
    for (int j = 0; j < 16; ++j) {
        int i = t + j * 256;
        if (i < cnt) {
            int2 p = pairs[i];
            int b = p.y >> BSHIFT;
            pairs_out[gpos[b] + (i - hstart[b])] = p;
        }
    }
}

// ---------------- K2d: per-bucket CSR fill + offs ---------------------------
__global__ __launch_bounds__(128) void csr_fill(
    const int2* __restrict__ pairs, const int* __restrict__ boff,
    int* __restrict__ offs, int* __restrict__ csr, int n)
{
    __shared__ int hist[128], pref[128], cur[128];
    int b = blockIdx.x, t = threadIdx.x;
    int base = boff[b], cnt = boff[b + 1] - base;
    int node0 = b << BSHIFT;
    hist[t] = 0;
    __syncthreads();
    for (int i = t; i < cnt; i += 128)
        atomicAdd(&hist[pairs[base + i].y & 127], 1);
    __syncthreads();
    if (t < 64) {
        int v0 = hist[2 * t], v1 = hist[2 * t + 1];
        int s = v0 + v1, inc = s;
        #pragma unroll
        for (int st = 1; st < 64; st <<= 1) {
            int u = __shfl_up(inc, st);
            if (t >= st) inc += u;
        }
        int ex = inc - s;
        pref[2 * t] = ex;       cur[2 * t] = ex;
        pref[2 * t + 1] = ex + v0; cur[2 * t + 1] = ex + v0;
    }
    __syncthreads();
    int node = node0 + t;
    if (node < n) offs[node] = base + pref[t];
    for (int i = t; i < cnt; i += 128) {
        int2 p = pairs[base + i];
        int pos = atomicAdd(&cur[p.y & 127], 1);
        csr[base + pos] = p.x;
    }
}

// ---------------- K5: per-node multi-stat reduction (1 wave / node) ---------
// bf16 A rows (128B): half-wave per edge -> 2 edges per load; 8-edge unroll
// keeps 4 independent gathers in flight (latency-bound fix).
__global__ __launch_bounds__(256) void node_reduce(
    const unsigned* __restrict__ Ab, const float* __restrict__ Bp,
    const float* __restrict__ bm,
    const int* __restrict__ offs, const int* __restrict__ csr,
    unsigned* __restrict__ hbu, float* __restrict__ s1, float* __restrict__ s2,
    int n, int npad)
{
    int wid = threadIdx.x >> 6;
    int lane = threadIdx.x & 63;
    int node = blockIdx.x * 4 + wid;
    if (node >= npad) return;
    unsigned* hrow = hbu + (size_t)node * 128;   // 256 bf16 = 128 uints
    int l32 = lane & 31;
    int half = lane >> 5;
    int beg = 0, dg = 0;
    if (node < n) { beg = offs[node]; dg = offs[node + 1] - beg; }
    if (dg == 0) {
        if (half == 0) {
            hrow[l32] = 0u; hrow[32 + l32] = 0u; hrow[64 + l32] = 0u; hrow[96 + l32] = 0u;
        }
        if (lane == 0) { s1[node] = 0.f; s2[node] = 0.f; }
        return;
    }

    float s0 = 0.f, s1a = 0.f, ss0 = 0.f, ss1 = 0.f;
    float mx0 = -FLT_BIG, mx1 = -FLT_BIG, mn0 = FLT_BIG, mn1 = FLT_BIG;

#define ACC(u) { float v0 = bflo(u), v1 = bfhi(u);                          \
    s0 += v0; s1a += v1;                                                    \
    ss0 = fmaf(v0, v0, ss0); ss1 = fmaf(v1, v1, ss1);                       \
    mx0 = fmaxf(mx0, v0); mx1 = fmaxf(mx1, v1);                             \
    mn0 = fminf(mn0, v0); mn1 = fminf(mn1, v1); }

    int j = beg, end = beg + dg;
    for (; j + 7 < end; j += 8) {           // 8 edges, 4 independent gathers
        int i0 = csr[j],     i1 = csr[j + 1], i2 = csr[j + 2], i3 = csr[j + 3];
        int i4 = csr[j + 4], i5 = csr[j + 5], i6 = csr[j + 6], i7 = csr[j + 7];
        int sa = half ? i1 : i0;
        int sb = half ? i3 : i2;
        int sc = half ? i5 : i4;
        int sd = half ? i7 : i6;
        unsigned ua = Ab[(size_t)sa * 32 + l32];
        unsigned ub = Ab[(size_t)sb * 32 + l32];
        unsigned uc = Ab[(size_t)sc * 32 + l32];
        unsigned ud = Ab[(size_t)sd * 32 + l32];
        ACC(ua); ACC(ub); ACC(uc); ACC(ud);
    }
    for (; j + 3 < end; j += 4) {
        int i0 = csr[j], i1 = csr[j + 1], i2 = csr[j + 2], i3 = csr[j + 3];
        int sa = half ? i1 : i0;
        int sb = half ? i3 : i2;
        unsigned ua = Ab[(size_t)sa * 32 + l32];
        unsigned ub = Ab[(size_t)sb * 32 + l32];
        ACC(ua); ACC(ub);
    }
    for (; j + 1 < end; j += 2) {
        int i0 = csr[j], i1 = csr[j + 1];
        int sa = half ? i1 : i0;
        unsigned ua = Ab[(size_t)sa * 32 + l32];
        ACC(ua);
    }
    if (j < end) {                          // odd tail: half 0 only
        int sa = csr[j];
        unsigned ua = Ab[(size_t)sa * 32 + l32];
        if (half == 0) ACC(ua);
    }
#undef ACC

    s0 += __shfl_xor(s0, 32);  s1a += __shfl_xor(s1a, 32);
    ss0 += __shfl_xor(ss0, 32); ss1 += __shfl_xor(ss1, 32);
    mx0 = fmaxf(mx0, __shfl_xor(mx0, 32)); mx1 = fmaxf(mx1, __shfl_xor(mx1, 32));
    mn0 = fminf(mn0, __shfl_xor(mn0, 32)); mn1 = fminf(mn1, __shfl_xor(mn1, 32));

    float fd = (float)dg, inv = 1.0f / fd;
    float2 bv = *(const float2*)(Bp + (size_t)node * 64 + 2 * l32);
    float2 bmv = *(const float2*)(bm + 2 * l32);
    float bn0 = bv.x + bmv.x, bn1 = bv.y + bmv.y;
    float ma0 = s0 * inv, ma1 = s1a * inv;
    float var0 = ss0 * inv - ma0 * ma0; if (var0 < 0.f) var0 = 0.f;
    float var1 = ss1 * inv - ma1 * ma1; if (var1 < 0.f) var1 = 0.f;
    float sd0 = sqrtf(var0 + MOM_EPS_C), sd1 = sqrtf(var1 + MOM_EPS_C);

    if (half == 0) {
        hrow[l32]      = pack2(ma0 + bn0, ma1 + bn1);
        hrow[32 + l32] = pack2(mx0 + bn0, mx1 + bn1);
        hrow[64 + l32] = pack2(mn0 + bn0, mn1 + bn1);
        hrow[96 + l32] = pack2(sd0, sd1);
    }
    if (lane == 0) {
        float logD = logf(fd + 1.0f);
        s1[node] = logD / DELTA_C;
        s2[node] = DELTA_C / logD;
    }
}

// ---------------- K6: MFMA update GEMM + fused BN column stats --------------
__global__ __launch_bounds__(256) void gemm_mfma(
    const short* __restrict__ xb, const short* __restrict__ hb,
    const float* __restrict__ s1p, const float* __restrict__ s2p,
    const short* __restrict__ Wup, const float* __restrict__ bu,
    float* __restrict__ z, float* __restrict__ bnacc, int n, float snorm)
{
    __shared__ float bnl[4][2][64];
    int t = threadIdx.x;
    int lane = t & 63, w = t >> 6;
    int rb = blockIdx.x * 128 + w * 32;
    int r16 = lane & 15, kg = lane >> 4;

    f32x4 accx[2][4] = {};
    f32x4 acc1[2][4] = {};
    f32x4 acc2[2][4] = {};
    f32x4 acc3[2][4] = {};

    const short* xr0 = xb + (size_t)(rb + r16) * 64 + kg * 8;
    const short* xr1 = xr0 + 16 * 64;

    #pragma unroll
    for (int kc = 0; kc < 2; ++kc) {
        bf16x8 a0 = *(const bf16x8*)(xr0 + kc * 32);
        bf16x8 a1 = *(const bf16x8*)(xr1 + kc * 32);
        #pragma unroll
        for (int c = 0; c < 4; ++c) {
            bf16x8 b = *(const bf16x8*)(Wup + (size_t)((kc * 4 + c) * 64 + lane) * 8);
            accx[0][c] = __builtin_amdgcn_mfma_f32_16x16x32_bf16(a0, b, accx[0][c], 0, 0, 0);
            accx[1][c] = __builtin_amdgcn_mfma_f32_16x16x32_bf16(a1, b, accx[1][c], 0, 0, 0);
        }
    }

    const short* hr0 = hb + (size_t)(rb + r16) * 256 + kg * 8;
    const short* hr1 = hr0 + 16 * 256;

    #pragma unroll 1
    for (int kh = 0; kh < 8; ++kh) {
        bf16x8 a0 = *(const bf16x8*)(hr0 + kh * 32);
        bf16x8 a1 = *(const bf16x8*)(hr1 + kh * 32);
        #pragma unroll
        for (int c = 0; c < 4; ++c) {
            bf16x8 b1 = *(const bf16x8*)(Wup + (size_t)(((2  + kh) * 4 + c) * 64 + lane) * 8);
            bf16x8 b2 = *(const bf16x8*)(Wup + (size_t)(((10 + kh) * 4 + c) * 64 + lane) * 8);
            bf16x8 b3 = *(const bf16x8*)(Wup + (size_t)(((18 + kh) * 4 + c) * 64 + lane) * 8);
            acc1[0][c] = __builtin_amdgcn_mfma_f32_16x16x32_bf16(a0, b1, acc1[0][c], 0, 0, 0);
            acc1[1][c] = __builtin_amdgcn_mfma_f32_16x16x32_bf16(a1, b1, acc1[1][c], 0, 0, 0);
            acc2[0][c] = __builtin_amdgcn_mfma_f32_16x16x32_bf16(a0, b2, acc2[0][c], 0, 0, 0);
            acc2[1][c] = __builtin_amdgcn_mfma_f32_16x16x32_bf16(a1, b2, acc2[1][c], 0, 0, 0);
            acc3[0][c] = __builtin_amdgcn_mfma_f32_16x16x32_bf16(a0, b3, acc3[0][c], 0, 0, 0);
            acc3[1][c] = __builtin_amdgcn_mfma_f32_16x16x32_bf16(a1, b3, acc3[1][c], 0, 0, 0);
        }
    }

    // epilogue: C/D frag layout col=lane&15, row=(lane>>4)*4+reg  [verified]
    float cs[4] = {}, css[4] = {};            // per-thread BN partials (4 cols)
    #pragma unroll
    for (int s = 0; s < 2; ++s) {
        int r0 = rb + s * 16 + kg * 4;
        float s1v[4], s2v[4];
        #pragma unroll
        for (int r = 0; r < 4; ++r) { s1v[r] = s1p[r0 + r]; s2v[r] = s2p[r0 + r]; }
        #pragma unroll
        for (int c = 0; c < 4; ++c) {
            int col = c * 16 + r16;
            float bval = bu[col];
            #pragma unroll
            for (int r = 0; r < 4; ++r) {
                int row = r0 + r;
                if (row < n) {
                    float v = (accx[s][c][r] + acc1[s][c][r]
                            + s1v[r] * acc2[s][c][r] + s2v[r] * acc3[s][c][r] + bval) * snorm;
                    z[(size_t)row * 64 + col] = v;
                    cs[c] += v;
                    css[c] = fmaf(v, v, css[c]);
                }
            }
        }
    }
    // butterfly over kg (lanes xor 16,32): all lanes end with the kg-sum
    #pragma unroll
    for (int c = 0; c < 4; ++c) {
        float a = cs[c];  a += __shfl_xor(a, 16); a += __shfl_xor(a, 32); cs[c] = a;
        float b = css[c]; b += __shfl_xor(b, 16); b += __shfl_xor(b, 32); css[c] = b;
    }
    if (lane < 16) {
        #pragma unroll
        for (int c = 0; c < 4; ++c) {
            bnl[w][0][c * 16 + lane] = cs[c];
            bnl[w][1][c * 16 + lane] = css[c];
        }
    }
    __syncthreads();
    if (t < 128) {
        int st = t >> 6, cc = t & 63;
        float tot = bnl[0][st][cc] + bnl[1][st][cc] + bnl[2][st][cc] + bnl[3][st][cc];
        atomicAdd(&bnacc[st * 64 + cc], tot);
    }
}

// ---------------- K8: BN normalize (in place on d_out) ----------------------
__global__ __launch_bounds__(256) void bn_apply(
    float* __restrict__ z, const float* __restrict__ acc,
    const float* __restrict__ gamma, const float* __restrict__ beta, int n)
{
    float inv_n = 1.0f / (float)n;
    int total = n * 64;
    for (int i = blockIdx.x * blockDim.x + threadIdx.x; i < total; i += gridDim.x * blockDim.x) {
        int c = i & 63;
        float mu = acc[c] * inv_n;
        float var = acc[64 + c] * inv_n - mu * mu;
        if (var < 0.f) var = 0.f;
        float inv = rsqrtf(var + BN_EPS_C);
        z[i] = (z[i] - mu) * inv * gamma[c] + beta[c];
    }
}

extern "C" void kernel_launch(void* const* d_in, const int* in_sizes, int n_in,
                              void* d_out, int out_size, void* d_ws, size_t ws_size,
                              hipStream_t stream)
{
    const float* x     = (const float*)d_in[0];
    const float* Wm    = (const float*)d_in[1];
    const float* bm    = (const float*)d_in[2];
    const float* Wu    = (const float*)d_in[3];
    const float* bu    = (const float*)d_in[4];
    const float* gamma = (const float*)d_in[5];
    const float* beta  = (const float*)d_in[6];
    const int*   src   = (const int*)d_in[7];
    const int*   dst   = (const int*)d_in[8];

    int n = in_sizes[0] / 64;
    int e = in_sizes[7];
    int npad = ((n + 127) / 128) * 128;
    int nb = (n + 127) >> BSHIFT;          // buckets (<=512 for n<=65536)
    float* z = (float*)d_out;

    char* w = (char*)d_ws;
    size_t off = 0;
    auto take = [&](size_t bytes) -> void* {
        void* p = w + off;
        off = (off + bytes + 255) & ~(size_t)255;
        return p;
    };
    unsigned* Ab    = (unsigned*)take((size_t)npad * 32 * sizeof(unsigned));
    float*    B     = (float*)take((size_t)n * 64 * sizeof(float));
    unsigned* xbu   = (unsigned*)take((size_t)npad * 32 * sizeof(unsigned));
    unsigned* hbu   = (unsigned*)take((size_t)npad * 128 * sizeof(unsigned));
    float*    s1    = (float*)take((size_t)npad * sizeof(float));
    float*    s2    = (float*)take((size_t)npad * sizeof(float));
    short*    Wup   = (short*)take((size_t)26 * 4 * 64 * 8 * sizeof(short));
    int*      offs  = (int*)take((size_t)(n + 1) * sizeof(int));
    int*      csr   = (int*)take((size_t)e * sizeof(int));
    int2*     prs   = (int2*)take((size_t)e * sizeof(int2));
    int*      bcnt  = (int*)take((size_t)NBMAX * sizeof(int));
    int*      boff  = (int*)take((size_t)(NBMAX + 1) * sizeof(int));
    int*      gcur  = (int*)take((size_t)NBMAX * sizeof(int));
    float*    bnacc = (float*)take(128 * sizeof(float));

    (void)n_in; (void)out_size; (void)ws_size;

    int nb_rows64 = npad / 64;
    int nb_chunk = (e + 4095) / 4096;

    init_small<<<1, 512, 0, stream>>>(bcnt, bnacc);
    repack_wu<<<26, 256, 0, stream>>>(Wu, Wup);
    proj_ab<<<nb_rows64, 256, 0, stream>>>(x, Wm, Ab, B, xbu, n);
    bin_count<<<nb_chunk, 256, 0, stream>>>(dst, bcnt, e);
    bin_scan<<<1, 64, 0, stream>>>(bcnt, boff, gcur, nb, offs, n, e);
    bin_scatter<<<nb_chunk, 256, 0, stream>>>(src, dst, gcur, prs, e);
    csr_fill<<<nb, 128, 0, stream>>>(prs, boff, offs, csr, n);
    node_reduce<<<(npad + 3) / 4, 256, 0, stream>>>(Ab, B, bm, offs, csr, hbu, s1, s2, n, npad);

    float snorm = (float)(1.0 / sqrt((double)n));
    gemm_mfma<<<npad / 128, 256, 0, stream>>>((const short*)xbu, (const short*)hbu,
                                              s1, s2, Wup, bu, z, bnacc, n, snorm);

    bn_apply<<<1024, 256, 0, stream>>>(z, bnacc, gamma, beta, n);
}